// Round 2
// baseline (277.506 us; speedup 1.0000x reference)
//
#include <hip/hip_runtime.h>

// Problem constants
#define B_N   2
#define H_LR  64
#define W_LR  64
#define HUP   128
#define WUP   128
#define GRP   4
#define NPT   9
#define EMB   32      // embedding dim per group (q/k)
#define CGRP  64      // x channels per group
#define KIN   256     // input channels for all convs
#define GE    128     // q/k channels
#define NOFF  288
#define NKOFF 416     // GE + NOFF

// ---------------------------------------------------------------------------
// Generic 1x1-conv GEMM: C[b, m, n] = bias[n] + sum_k W[n,k] * X[b, k, m]
// Output pixel-major. W/bias are a concat of (W1,b1) rows [0,N1) and (W2,b2)
// rows [N1,N). BM=64 (pixels), BN=64 (out ch), BK=32, 256 threads.
// ---------------------------------------------------------------------------
__global__ __launch_bounds__(256) void conv1x1_kernel(
    const float* __restrict__ X, const float* __restrict__ W1,
    const float* __restrict__ b1, const float* __restrict__ W2,
    const float* __restrict__ b2, float* __restrict__ C,
    int M, int N, int N1, int mtiles, int ntiles)
{
    __shared__ float sX[32][72];
    __shared__ float sW[32][72];
    int bx = blockIdx.x;
    int mt = bx % mtiles;
    int nt = (bx / mtiles) % ntiles;
    int b  = bx / (mtiles * ntiles);
    int m0 = mt * 64, n0 = nt * 64;
    int tid = threadIdx.x;
    int tx = tid & 15, ty = tid >> 4;

    float acc[4][4];
#pragma unroll
    for (int i = 0; i < 4; ++i)
#pragma unroll
        for (int j = 0; j < 4; ++j) acc[i][j] = 0.f;

    const float* Xb = X + (size_t)b * KIN * M;

    for (int k0 = 0; k0 < KIN; k0 += 32) {
#pragma unroll
        for (int r = 0; r < 8; ++r) {           // X tile: coalesced along m
            int idx = tid + r * 256;
            int kk = idx >> 6, mm = idx & 63;
            sX[kk][mm] = Xb[(size_t)(k0 + kk) * M + m0 + mm];
        }
#pragma unroll
        for (int r = 0; r < 8; ++r) {           // W tile: coalesced along k
            int idx = tid + r * 256;
            int kk = idx & 31, nn = idx >> 5;
            int n = n0 + nn;
            float v = 0.f;
            if (n < N)
                v = (n < N1) ? W1[(size_t)n * KIN + k0 + kk]
                             : W2[(size_t)(n - N1) * KIN + k0 + kk];
            sW[kk][nn] = v;
        }
        __syncthreads();
#pragma unroll
        for (int kk = 0; kk < 32; ++kk) {
            float xv[4], wv[4];
#pragma unroll
            for (int i = 0; i < 4; ++i) xv[i] = sX[kk][tx * 4 + i];
#pragma unroll
            for (int j = 0; j < 4; ++j) wv[j] = sW[kk][ty * 4 + j];
#pragma unroll
            for (int i = 0; i < 4; ++i)
#pragma unroll
                for (int j = 0; j < 4; ++j) acc[i][j] += xv[i] * wv[j];
        }
        __syncthreads();
    }

    int n = n0 + ty * 4;
    if (n < N) {
        float bb[4];
#pragma unroll
        for (int j = 0; j < 4; ++j) {
            int nn = n + j;
            bb[j] = (nn < N1) ? b1[nn] : b2[nn - N1];
        }
#pragma unroll
        for (int i = 0; i < 4; ++i) {
            int m = m0 + tx * 4 + i;
            float4 v;
            v.x = acc[i][0] + bb[0];
            v.y = acc[i][1] + bb[1];
            v.z = acc[i][2] + bb[2];
            v.w = acc[i][3] + bb[3];
            *(float4*)&C[((size_t)b * M + m) * N + n] = v;
        }
    }
}

// ---------------------------------------------------------------------------
// Transpose x [B, 256, 4096] -> xT [B, 4096, 256]  (pixel-major)
// ---------------------------------------------------------------------------
__global__ __launch_bounds__(256) void transpose_kernel(
    const float* __restrict__ X, float* __restrict__ XT)
{
    __shared__ float tile[32][33];
    int bx = blockIdx.x;
    int mt = bx % 128;
    int ct = (bx / 128) % 8;
    int b  = bx / 1024;
    int tid = threadIdx.x;
    int lx = tid & 31, lyb = tid >> 5;   // 8 rows per pass, 4 passes
#pragma unroll
    for (int r = 0; r < 4; ++r) {
        int c = ct * 32 + lyb + r * 8;
        int m = mt * 32 + lx;
        tile[lyb + r * 8][lx] = X[((size_t)b * 256 + c) * 4096 + m];
    }
    __syncthreads();
#pragma unroll
    for (int r = 0; r < 4; ++r) {
        int m = mt * 32 + lyb + r * 8;
        int c = ct * 32 + lx;
        XT[((size_t)b * 4096 + m) * 256 + c] = tile[lx][lyb + r * 8];
    }
}

// ---------------------------------------------------------------------------
// Fused deformable attention, phase-split for occupancy.
// Block = 256 threads = 4 roles x 64 pixels (16x4 up-pixel tile, one (b,g)).
// Grid = 2 * 4 * 8 * 32 = 2048 blocks.
// Phase A: role = bilinear corner; per-corner weighted partial q.k dots -> LDS
// Phase A2: one wave reduces corners + softmax -> normalized attn in LDS
// Phase B: role = channel quarter; 16-channel weighted gather of x
// ---------------------------------------------------------------------------
__global__ __launch_bounds__(256, 4) void deform_kernel(
    const float* __restrict__ qws,   // [B, HUP*WUP, 128] pixel-major
    const float* __restrict__ koff,  // [B, 4096, 416]: n<128 = k, n>=128 = off
    const float* __restrict__ xT,    // [B, 4096, 256] pixel-major
    float* __restrict__ out)         // [B, 256, HUP, WUP]
{
    __shared__ float sPart[NPT * 4 * 64];   // [p][corner][pix]
    __shared__ float sPy[NPT * 64];         // [p][pix]
    __shared__ float sPx[NPT * 64];
    __shared__ float sAttn[NPT * 64];       // normalized attn

    int bx = blockIdx.x;
    int tw = bx & 7;               // 8 tiles of 16 along W
    int th = (bx >> 3) & 31;       // 32 tiles of 4 along H
    int g  = (bx >> 8) & 3;
    int b  = bx >> 10;

    int tid  = threadIdx.x;
    int pix  = tid & 63;
    int role = tid >> 6;           // wave index

    int lx = pix & 15, ly = pix >> 4;
    int wup = tw * 16 + lx, hup = th * 4 + ly;
    int h = hup >> 1, w = wup >> 1;
    int ij = (hup & 1) * 2 + (wup & 1);
    int pixlr = h * W_LR + w;

    const float* kb = koff + ((size_t)b * 4096 + pixlr) * NKOFF;
    float by  = (hup + 0.5f) * 0.5f - 0.5f;
    float bxx = (wup + 0.5f) * 0.5f - 0.5f;

    // ---------------- Phase A: per-corner partial attention logits ---------
    {
        int dy = role >> 1, dx = role & 1;
        const float* qp = qws + ((size_t)b * (HUP * WUP) + hup * WUP + wup) * GE + g * EMB;
        float4 q[8];
#pragma unroll
        for (int r = 0; r < 8; ++r) q[r] = ((const float4*)qp)[r];

#pragma unroll
        for (int p = 0; p < NPT; ++p) {
            float offy = kb[GE + ((g * NPT + p) * 2 + 0) * 4 + ij];
            float offx = kb[GE + ((g * NPT + p) * 2 + 1) * 4 + ij];
            float py = offy + by, px = offx + bxx;
            if (role == 0) { sPy[p * 64 + pix] = py; sPx[p * 64 + pix] = px; }
            float y0f = floorf(py), x0f = floorf(px);
            float ty = py - y0f, tx = px - x0f;
            int yy = (int)y0f + dy, xx = (int)x0f + dx;
            float partial = 0.f;
            if (yy >= 0 && yy < H_LR && xx >= 0 && xx < W_LR) {
                float wv = (dy ? ty : 1.f - ty) * (dx ? tx : 1.f - tx);
                const float4* kr = (const float4*)(
                    koff + ((size_t)b * 4096 + yy * W_LR + xx) * NKOFF + g * EMB);
                float dot = 0.f;
#pragma unroll
                for (int r = 0; r < 8; ++r) {
                    float4 kv = kr[r];
                    dot += q[r].x * kv.x + q[r].y * kv.y +
                           q[r].z * kv.z + q[r].w * kv.w;
                }
                partial = wv * dot;
            }
            sPart[(p * 4 + role) * 64 + pix] = partial;
        }
    }
    __syncthreads();

    // ---------------- Phase A2: reduce corners + softmax (one wave) --------
    if (tid < 64) {
        float a[NPT];
#pragma unroll
        for (int p = 0; p < NPT; ++p) {
            a[p] = sPart[(p * 4 + 0) * 64 + tid] + sPart[(p * 4 + 1) * 64 + tid] +
                   sPart[(p * 4 + 2) * 64 + tid] + sPart[(p * 4 + 3) * 64 + tid];
        }
        float mx = a[0];
#pragma unroll
        for (int p = 1; p < NPT; ++p) mx = fmaxf(mx, a[p]);
        float s = 0.f;
#pragma unroll
        for (int p = 0; p < NPT; ++p) { a[p] = __expf(a[p] - mx); s += a[p]; }
        float inv = 1.f / s;
#pragma unroll
        for (int p = 0; p < NPT; ++p) sAttn[p * 64 + tid] = a[p] * inv;
    }
    __syncthreads();

    // ---------------- Phase B: weighted gather of x (16 channels/thread) ---
    {
        int qtr = role;
        float4 acc[4];
#pragma unroll
        for (int r = 0; r < 4; ++r) acc[r] = make_float4(0.f, 0.f, 0.f, 0.f);

#pragma unroll
        for (int p = 0; p < NPT; ++p) {
            float ap = sAttn[p * 64 + pix];
            float py = sPy[p * 64 + pix], px = sPx[p * 64 + pix];
            float y0f = floorf(py), x0f = floorf(px);
            float ty = py - y0f, tx = px - x0f;
            int y0 = (int)y0f, x0 = (int)x0f;
#pragma unroll
            for (int cy = 0; cy < 2; ++cy)
#pragma unroll
                for (int cx = 0; cx < 2; ++cx) {
                    int yy = y0 + cy, xx = x0 + cx;
                    if (yy >= 0 && yy < H_LR && xx >= 0 && xx < W_LR) {
                        float wv = ap * (cy ? ty : 1.f - ty) * (cx ? tx : 1.f - tx);
                        const float4* xr = (const float4*)(
                            xT + ((size_t)b * 4096 + yy * W_LR + xx) * 256 +
                            g * CGRP + qtr * 16);
#pragma unroll
                        for (int r = 0; r < 4; ++r) {
                            float4 xv = xr[r];
                            acc[r].x += wv * xv.x; acc[r].y += wv * xv.y;
                            acc[r].z += wv * xv.z; acc[r].w += wv * xv.w;
                        }
                    }
                }
        }

        float* ob = out + ((size_t)b * 256 + g * CGRP + qtr * 16) * (HUP * WUP) +
                    hup * WUP + wup;
#pragma unroll
        for (int r = 0; r < 4; ++r) {
            ob[(size_t)(r * 4 + 0) * (HUP * WUP)] = acc[r].x;
            ob[(size_t)(r * 4 + 1) * (HUP * WUP)] = acc[r].y;
            ob[(size_t)(r * 4 + 2) * (HUP * WUP)] = acc[r].z;
            ob[(size_t)(r * 4 + 3) * (HUP * WUP)] = acc[r].w;
        }
    }
}

// ---------------------------------------------------------------------------
extern "C" void kernel_launch(void* const* d_in, const int* in_sizes, int n_in,
                              void* d_out, int out_size, void* d_ws, size_t ws_size,
                              hipStream_t stream)
{
    const float* y    = (const float*)d_in[0];
    const float* x    = (const float*)d_in[1];
    const float* Wq   = (const float*)d_in[2];
    const float* bq   = (const float*)d_in[3];
    const float* Wk   = (const float*)d_in[4];
    const float* bk   = (const float*)d_in[5];
    const float* Woff = (const float*)d_in[6];
    const float* boff = (const float*)d_in[7];
    float* out = (float*)d_out;

    float* qws    = (float*)d_ws;                             // 2*16384*128 floats
    float* koffws = qws + (size_t)B_N * HUP * WUP * GE;       // 2*4096*416 floats
    float* xTws   = koffws + (size_t)B_N * H_LR * W_LR * NKOFF; // 2*4096*256 floats

    // q = Wq @ y + bq, pixel-major [B, 16384, 128]
    conv1x1_kernel<<<dim3(B_N * 256 * 2), dim3(256), 0, stream>>>(
        y, Wq, bq, nullptr, nullptr, qws, HUP * WUP, GE, GE, 256, 2);

    // concat(k, off) = [Wk;Woff] @ x + [bk;boff], pixel-major [B, 4096, 416]
    conv1x1_kernel<<<dim3(B_N * 64 * 7), dim3(256), 0, stream>>>(
        x, Wk, bk, Woff, boff, koffws, H_LR * W_LR, NKOFF, GE, 64, 7);

    // xT [B, 4096, 256]
    transpose_kernel<<<dim3(2048), dim3(256), 0, stream>>>(x, xTws);

    // fused deformable attention
    deform_kernel<<<dim3(2048), dim3(256), 0, stream>>>(qws, koffws, xTws, out);
}

// Round 3
// 194.172 us; speedup vs baseline: 1.4292x; 1.4292x over previous
//
#include <hip/hip_runtime.h>

// Problem constants
#define B_N   2
#define H_LR  64
#define W_LR  64
#define HUP   128
#define WUP   128
#define GRP   4
#define NPT   9
#define EMB   32      // embedding dim per group (q/k)
#define CGRP  64      // x channels per group
#define KIN   256     // input channels for all convs
#define GE    128     // q/k channels
#define NOFF  288
#define NKOFF 416     // GE + NOFF

// ---------------------------------------------------------------------------
// Generic 1x1-conv GEMM: C[b, m, n] = bias[n] + sum_k W[n,k] * X[b, k, m]
// ---------------------------------------------------------------------------
__global__ __launch_bounds__(256) void conv1x1_kernel(
    const float* __restrict__ X, const float* __restrict__ W1,
    const float* __restrict__ b1, const float* __restrict__ W2,
    const float* __restrict__ b2, float* __restrict__ C,
    int M, int N, int N1, int mtiles, int ntiles)
{
    __shared__ float sX[32][72];
    __shared__ float sW[32][72];
    int bx = blockIdx.x;
    int mt = bx % mtiles;
    int nt = (bx / mtiles) % ntiles;
    int b  = bx / (mtiles * ntiles);
    int m0 = mt * 64, n0 = nt * 64;
    int tid = threadIdx.x;
    int tx = tid & 15, ty = tid >> 4;

    float acc[4][4];
#pragma unroll
    for (int i = 0; i < 4; ++i)
#pragma unroll
        for (int j = 0; j < 4; ++j) acc[i][j] = 0.f;

    const float* Xb = X + (size_t)b * KIN * M;

    for (int k0 = 0; k0 < KIN; k0 += 32) {
#pragma unroll
        for (int r = 0; r < 8; ++r) {
            int idx = tid + r * 256;
            int kk = idx >> 6, mm = idx & 63;
            sX[kk][mm] = Xb[(size_t)(k0 + kk) * M + m0 + mm];
        }
#pragma unroll
        for (int r = 0; r < 8; ++r) {
            int idx = tid + r * 256;
            int kk = idx & 31, nn = idx >> 5;
            int n = n0 + nn;
            float v = 0.f;
            if (n < N)
                v = (n < N1) ? W1[(size_t)n * KIN + k0 + kk]
                             : W2[(size_t)(n - N1) * KIN + k0 + kk];
            sW[kk][nn] = v;
        }
        __syncthreads();
#pragma unroll
        for (int kk = 0; kk < 32; ++kk) {
            float xv[4], wv[4];
#pragma unroll
            for (int i = 0; i < 4; ++i) xv[i] = sX[kk][tx * 4 + i];
#pragma unroll
            for (int j = 0; j < 4; ++j) wv[j] = sW[kk][ty * 4 + j];
#pragma unroll
            for (int i = 0; i < 4; ++i)
#pragma unroll
                for (int j = 0; j < 4; ++j) acc[i][j] += xv[i] * wv[j];
        }
        __syncthreads();
    }

    int n = n0 + ty * 4;
    if (n < N) {
        float bb[4];
#pragma unroll
        for (int j = 0; j < 4; ++j) {
            int nn = n + j;
            bb[j] = (nn < N1) ? b1[nn] : b2[nn - N1];
        }
#pragma unroll
        for (int i = 0; i < 4; ++i) {
            int m = m0 + tx * 4 + i;
            float4 v;
            v.x = acc[i][0] + bb[0];
            v.y = acc[i][1] + bb[1];
            v.z = acc[i][2] + bb[2];
            v.w = acc[i][3] + bb[3];
            *(float4*)&C[((size_t)b * M + m) * N + n] = v;
        }
    }
}

// ---------------------------------------------------------------------------
// Transpose x [B, 256, 4096] -> xT [B, 4096, 256]  (pixel-major)
// ---------------------------------------------------------------------------
__global__ __launch_bounds__(256) void transpose_kernel(
    const float* __restrict__ X, float* __restrict__ XT)
{
    __shared__ float tile[32][33];
    int bx = blockIdx.x;
    int mt = bx % 128;
    int ct = (bx / 128) % 8;
    int b  = bx / 1024;
    int tid = threadIdx.x;
    int lx = tid & 31, lyb = tid >> 5;
#pragma unroll
    for (int r = 0; r < 4; ++r) {
        int c = ct * 32 + lyb + r * 8;
        int m = mt * 32 + lx;
        tile[lyb + r * 8][lx] = X[((size_t)b * 256 + c) * 4096 + m];
    }
    __syncthreads();
#pragma unroll
    for (int r = 0; r < 4; ++r) {
        int m = mt * 32 + lyb + r * 8;
        int c = ct * 32 + lx;
        XT[((size_t)b * 4096 + m) * 256 + c] = tile[lx][lyb + r * 8];
    }
}

// ---------------------------------------------------------------------------
// Fused deformable attention — coalesced cooperative gathers.
// Block = 256 threads (4 waves) = one (b,g) x 16x4 up-pixel tile (64 px).
// Phase A: 16 lanes per (pixel,point): 4 corners x 4 chunks of 8 channels;
//          quad-contiguous k loads; shfl_xor tree -> attention logit.
// Phase B: 16 lanes per up-pixel = 16 float4 covering the 64-ch x row
//          (fully coalesced); 4 up-pixels per wave in lockstep.
// Phase C: LDS transpose -> coalesced stores.
// ---------------------------------------------------------------------------
__global__ __launch_bounds__(256, 4) void deform_kernel(
    const float* __restrict__ qws,   // [B, 16384, 128] pixel-major
    const float* __restrict__ koff,  // [B, 4096, 416]: n<128 = k, n>=128 = off
    const float* __restrict__ xT,    // [B, 4096, 256] pixel-major
    float* __restrict__ out)         // [B, 256, 128, 128]
{
    __shared__ float sOff[16 * 72];          // [lr][72] offset slice for group g
    __shared__ float sQ[64 * 36];            // [px][36] q slice (pad to 144B rows)
    __shared__ float sPy[64 * 9];            // [px][p]
    __shared__ float sPx[64 * 9];
    __shared__ float sAttn[64 * 9];          // logits, then normalized attn
    __shared__ float sOut[64 * 65];          // [c][px] transposed output tile

    int bx = blockIdx.x;
    int tw = bx & 7, th = (bx >> 3) & 31, g = (bx >> 8) & 3, b = bx >> 10;
    int tid = threadIdx.x;
    int wv_ = tid >> 6;
    int lane = tid & 63;

    const size_t kbase = (size_t)b * 4096 * NKOFF;

    // ---------------- Phase 0: stage offsets + q into LDS ------------------
    {
        int lr_x0 = tw * 8, lr_y0 = th * 2;
#pragma unroll
        for (int r = 0; r < 2; ++r) {
            int idx = tid + r * 256;
            if (idx < 288) {
                int lr = idx / 18, f4 = idx % 18;
                int yy = lr_y0 + (lr >> 3), xx = lr_x0 + (lr & 7);
                float4 v = *(const float4*)&koff[kbase + (size_t)(yy * W_LR + xx) * NKOFF +
                                                 GE + g * 72 + f4 * 4];
                *(float4*)&sOff[lr * 72 + f4 * 4] = v;
            }
        }
#pragma unroll
        for (int r = 0; r < 2; ++r) {
            int idx = tid + r * 256;              // 0..511
            int px = idx >> 3, f4 = idx & 7;
            int hup = th * 4 + (px >> 4), wup = tw * 16 + (px & 15);
            float4 v = *(const float4*)&qws[((size_t)b * 16384 + hup * 128 + wup) * GE +
                                            g * EMB + f4 * 4];
            *(float4*)&sQ[px * 36 + f4 * 4] = v;
        }
    }
    __syncthreads();

    // ---------------- Phase A: attention logits ----------------------------
    {
        int pslot  = lane >> 4;
        int corner = (lane >> 2) & 3;
        int chunk  = lane & 3;
        int dy = corner >> 1, dx = corner & 1;

        int pix = wv_ * 16 + (pslot / 9);        // pslot<4 -> pix offset 0
        int p   = pslot;                          // f = pslot initially

        for (int it = 0; it < 36; ++it) {
            int lx = pix & 15, ly = (pix >> 4) & 3;
            int hup = th * 4 + ly, wup = tw * 16 + lx;
            int lr  = (ly >> 1) * 8 + (lx >> 1);
            int ij  = ((ly & 1) << 1) | (lx & 1);

            float offy = sOff[lr * 72 + p * 8 + ij];
            float offx = sOff[lr * 72 + p * 8 + 4 + ij];
            float py  = offy + (hup + 0.5f) * 0.5f - 0.5f;
            float px_ = offx + (wup + 0.5f) * 0.5f - 0.5f;
            float y0f = floorf(py), x0f = floorf(px_);
            float ty = py - y0f, tx = px_ - x0f;
            int yy = (int)y0f + dy, xx = (int)x0f + dx;
            bool valid = (yy >= 0 && yy < H_LR && xx >= 0 && xx < W_LR);
            float wgt = (dy ? ty : 1.f - ty) * (dx ? tx : 1.f - tx);
            int yc = min(max(yy, 0), H_LR - 1), xc = min(max(xx, 0), W_LR - 1);

            const float4* kr = (const float4*)&koff[kbase + (size_t)(yc * W_LR + xc) * NKOFF +
                                                    g * EMB + chunk * 8];
            float4 k0 = kr[0], k1 = kr[1];
            const float4* qr = (const float4*)&sQ[pix * 36 + chunk * 8];
            float4 q0 = qr[0], q1 = qr[1];
            float d = k0.x * q0.x + k0.y * q0.y + k0.z * q0.z + k0.w * q0.w +
                      k1.x * q1.x + k1.y * q1.y + k1.z * q1.z + k1.w * q1.w;
            d = valid ? d * wgt : 0.f;
            d += __shfl_xor(d, 1);
            d += __shfl_xor(d, 2);
            d += __shfl_xor(d, 4);
            d += __shfl_xor(d, 8);
            if ((lane & 15) == 0) {
                sAttn[pix * 9 + p] = d;
                sPy[pix * 9 + p] = py;
                sPx[pix * 9 + p] = px_;
            }
            // advance item: f += 4  ->  p += 4 (mod 9), pix += carry
            p += 4;
            int c = (p >= 9);
            p -= 9 * c;
            pix += c;
        }
    }
    __syncthreads();

    // ---------------- Softmax over 9 points (one pixel per thread) ---------
    if (tid < 64) {
        float a[NPT];
        float mx = -1e30f;
#pragma unroll
        for (int p = 0; p < NPT; ++p) { a[p] = sAttn[tid * 9 + p]; mx = fmaxf(mx, a[p]); }
        float s = 0.f;
#pragma unroll
        for (int p = 0; p < NPT; ++p) { a[p] = __expf(a[p] - mx); s += a[p]; }
        float inv = 1.f / s;
#pragma unroll
        for (int p = 0; p < NPT; ++p) sAttn[tid * 9 + p] = a[p] * inv;
    }
    __syncthreads();

    // ---------------- Phase B: weighted coalesced gather of x --------------
    {
        int pg = lane >> 4, c4 = lane & 15;      // pixel-group, channel quad
        const size_t xch = (size_t)b * 4096 * 256 + g * CGRP + c4 * 4;

#pragma unroll
        for (int sub = 0; sub < 4; ++sub) {
            int pix = wv_ * 16 + sub * 4 + pg;
            float4 acc = make_float4(0.f, 0.f, 0.f, 0.f);
#pragma unroll
            for (int p = 0; p < NPT; ++p) {
                float ap  = sAttn[pix * 9 + p];
                float py  = sPy[pix * 9 + p];
                float px_ = sPx[pix * 9 + p];
                float y0f = floorf(py), x0f = floorf(px_);
                float ty = py - y0f, tx = px_ - x0f;
                int y0 = (int)y0f, x0 = (int)x0f;
#pragma unroll
                for (int cy = 0; cy < 2; ++cy)
#pragma unroll
                    for (int cx = 0; cx < 2; ++cx) {
                        int yy = y0 + cy, xx = x0 + cx;
                        if (yy >= 0 && yy < H_LR && xx >= 0 && xx < W_LR) {
                            float w = ap * (cy ? ty : 1.f - ty) * (cx ? tx : 1.f - tx);
                            float4 xv = *(const float4*)&xT[xch + (size_t)(yy * W_LR + xx) * 256];
                            acc.x += w * xv.x; acc.y += w * xv.y;
                            acc.z += w * xv.z; acc.w += w * xv.w;
                        }
                    }
            }
            // transposed write: sOut[c][pix], 2-way (free) bank pattern
            int cb = c4 * 4;
            sOut[(cb + 0) * 65 + pix] = acc.x;
            sOut[(cb + 1) * 65 + pix] = acc.y;
            sOut[(cb + 2) * 65 + pix] = acc.z;
            sOut[(cb + 3) * 65 + pix] = acc.w;
        }
    }
    __syncthreads();

    // ---------------- Phase C: coalesced store -----------------------------
    {
        int pix = tid & 63, c0 = tid >> 6;
        int lx = pix & 15, ly = pix >> 4;
        int hup = th * 4 + ly, wup = tw * 16 + lx;
        float* ob = out + ((size_t)b * 256 + g * CGRP) * (HUP * WUP) + hup * WUP + wup;
#pragma unroll
        for (int k = 0; k < 16; ++k) {
            int c = k * 4 + c0;
            ob[(size_t)c * (HUP * WUP)] = sOut[c * 65 + pix];
        }
    }
}

// ---------------------------------------------------------------------------
extern "C" void kernel_launch(void* const* d_in, const int* in_sizes, int n_in,
                              void* d_out, int out_size, void* d_ws, size_t ws_size,
                              hipStream_t stream)
{
    const float* y    = (const float*)d_in[0];
    const float* x    = (const float*)d_in[1];
    const float* Wq   = (const float*)d_in[2];
    const float* bq   = (const float*)d_in[3];
    const float* Wk   = (const float*)d_in[4];
    const float* bk   = (const float*)d_in[5];
    const float* Woff = (const float*)d_in[6];
    const float* boff = (const float*)d_in[7];
    float* out = (float*)d_out;

    float* qws    = (float*)d_ws;
    float* koffws = qws + (size_t)B_N * HUP * WUP * GE;
    float* xTws   = koffws + (size_t)B_N * H_LR * W_LR * NKOFF;

    conv1x1_kernel<<<dim3(B_N * 256 * 2), dim3(256), 0, stream>>>(
        y, Wq, bq, nullptr, nullptr, qws, HUP * WUP, GE, GE, 256, 2);

    conv1x1_kernel<<<dim3(B_N * 64 * 7), dim3(256), 0, stream>>>(
        x, Wk, bk, Woff, boff, koffws, H_LR * W_LR, NKOFF, GE, 64, 7);

    transpose_kernel<<<dim3(2048), dim3(256), 0, stream>>>(x, xTws);

    deform_kernel<<<dim3(2048), dim3(256), 0, stream>>>(qws, koffws, xTws, out);
}

// Round 4
// 181.090 us; speedup vs baseline: 1.5324x; 1.0722x over previous
//
#include <hip/hip_runtime.h>

// Problem constants
#define B_N   2
#define H_LR  64
#define W_LR  64
#define HUP   128
#define WUP   128
#define GRP   4
#define NPT   9
#define EMB   32      // embedding dim per group (q/k)
#define CGRP  64      // x channels per group
#define KIN   256     // input channels for all convs
#define GE    128     // q/k channels
#define NOFF  288
#define NKOFF 416     // GE + NOFF

// ---------------------------------------------------------------------------
// conv q: Q[b, m, n] = bq[n] + sum_k Wq[n,k] * Y[b,k,m]; N=128 single n-tile
// BM=64, BN=128, BK=32, 256 threads, acc 4x8. y read exactly once.
// ---------------------------------------------------------------------------
__global__ __launch_bounds__(256) void conv_q_kernel(
    const float* __restrict__ Y, const float* __restrict__ Wq,
    const float* __restrict__ bq, float* __restrict__ Q)
{
    __shared__ float sX[32][72];
    __shared__ float sW[32][136];
    int bx = blockIdx.x;
    int mt = bx & 255, b = bx >> 8;
    int m0 = mt * 64;
    int tid = threadIdx.x;
    int tx = tid & 15, ty = tid >> 4;

    float acc[4][8];
#pragma unroll
    for (int i = 0; i < 4; ++i)
#pragma unroll
        for (int j = 0; j < 8; ++j) acc[i][j] = 0.f;

    const float* Yb = Y + (size_t)b * KIN * 16384;

    for (int k0 = 0; k0 < KIN; k0 += 32) {
#pragma unroll
        for (int r = 0; r < 8; ++r) {
            int idx = tid + r * 256;
            int kk = idx >> 6, mm = idx & 63;
            sX[kk][mm] = Yb[(size_t)(k0 + kk) * 16384 + m0 + mm];
        }
#pragma unroll
        for (int r = 0; r < 16; ++r) {
            int idx = tid + r * 256;
            int kk = idx & 31, nn = idx >> 5;
            sW[kk][nn] = Wq[(size_t)nn * KIN + k0 + kk];
        }
        __syncthreads();
#pragma unroll
        for (int kk = 0; kk < 32; ++kk) {
            float xv[4], wv[8];
#pragma unroll
            for (int i = 0; i < 4; ++i) xv[i] = sX[kk][tx * 4 + i];
#pragma unroll
            for (int j = 0; j < 8; ++j) wv[j] = sW[kk][ty * 8 + j];
#pragma unroll
            for (int i = 0; i < 4; ++i)
#pragma unroll
                for (int j = 0; j < 8; ++j) acc[i][j] += xv[i] * wv[j];
        }
        __syncthreads();
    }

    int n = ty * 8;
    float bb[8];
#pragma unroll
    for (int j = 0; j < 8; ++j) bb[j] = bq[n + j];
#pragma unroll
    for (int i = 0; i < 4; ++i) {
        int m = m0 + tx * 4 + i;
        float4 v0, v1;
        v0.x = acc[i][0] + bb[0]; v0.y = acc[i][1] + bb[1];
        v0.z = acc[i][2] + bb[2]; v0.w = acc[i][3] + bb[3];
        v1.x = acc[i][4] + bb[4]; v1.y = acc[i][5] + bb[5];
        v1.z = acc[i][6] + bb[6]; v1.w = acc[i][7] + bb[7];
        *(float4*)&Q[((size_t)b * 16384 + m) * GE + n] = v0;
        *(float4*)&Q[((size_t)b * 16384 + m) * GE + n + 4] = v1;
    }
}

// ---------------------------------------------------------------------------
// Generic 1x1-conv GEMM (used for concat(k,off)):
// C[b, m, n] = bias[n] + sum_k W[n,k] * X[b, k, m]
// ---------------------------------------------------------------------------
__global__ __launch_bounds__(256) void conv1x1_kernel(
    const float* __restrict__ X, const float* __restrict__ W1,
    const float* __restrict__ b1, const float* __restrict__ W2,
    const float* __restrict__ b2, float* __restrict__ C,
    int M, int N, int N1, int mtiles, int ntiles)
{
    __shared__ float sX[32][72];
    __shared__ float sW[32][72];
    int bx = blockIdx.x;
    int mt = bx % mtiles;
    int nt = (bx / mtiles) % ntiles;
    int b  = bx / (mtiles * ntiles);
    int m0 = mt * 64, n0 = nt * 64;
    int tid = threadIdx.x;
    int tx = tid & 15, ty = tid >> 4;

    float acc[4][4];
#pragma unroll
    for (int i = 0; i < 4; ++i)
#pragma unroll
        for (int j = 0; j < 4; ++j) acc[i][j] = 0.f;

    const float* Xb = X + (size_t)b * KIN * M;

    for (int k0 = 0; k0 < KIN; k0 += 32) {
#pragma unroll
        for (int r = 0; r < 8; ++r) {
            int idx = tid + r * 256;
            int kk = idx >> 6, mm = idx & 63;
            sX[kk][mm] = Xb[(size_t)(k0 + kk) * M + m0 + mm];
        }
#pragma unroll
        for (int r = 0; r < 8; ++r) {
            int idx = tid + r * 256;
            int kk = idx & 31, nn = idx >> 5;
            int n = n0 + nn;
            float v = 0.f;
            if (n < N)
                v = (n < N1) ? W1[(size_t)n * KIN + k0 + kk]
                             : W2[(size_t)(n - N1) * KIN + k0 + kk];
            sW[kk][nn] = v;
        }
        __syncthreads();
#pragma unroll
        for (int kk = 0; kk < 32; ++kk) {
            float xv[4], wv[4];
#pragma unroll
            for (int i = 0; i < 4; ++i) xv[i] = sX[kk][tx * 4 + i];
#pragma unroll
            for (int j = 0; j < 4; ++j) wv[j] = sW[kk][ty * 4 + j];
#pragma unroll
            for (int i = 0; i < 4; ++i)
#pragma unroll
                for (int j = 0; j < 4; ++j) acc[i][j] += xv[i] * wv[j];
        }
        __syncthreads();
    }

    int n = n0 + ty * 4;
    if (n < N) {
        float bb[4];
#pragma unroll
        for (int j = 0; j < 4; ++j) {
            int nn = n + j;
            bb[j] = (nn < N1) ? b1[nn] : b2[nn - N1];
        }
#pragma unroll
        for (int i = 0; i < 4; ++i) {
            int m = m0 + tx * 4 + i;
            float4 v;
            v.x = acc[i][0] + bb[0];
            v.y = acc[i][1] + bb[1];
            v.z = acc[i][2] + bb[2];
            v.w = acc[i][3] + bb[3];
            *(float4*)&C[((size_t)b * M + m) * N + n] = v;
        }
    }
}

// ---------------------------------------------------------------------------
// Transpose x [B, 256, 4096] -> xT [B, 4096, 256]  (pixel-major)
// ---------------------------------------------------------------------------
__global__ __launch_bounds__(256) void transpose_kernel(
    const float* __restrict__ X, float* __restrict__ XT)
{
    __shared__ float tile[32][33];
    int bx = blockIdx.x;
    int mt = bx % 128;
    int ct = (bx / 128) % 8;
    int b  = bx / 1024;
    int tid = threadIdx.x;
    int lx = tid & 31, lyb = tid >> 5;
#pragma unroll
    for (int r = 0; r < 4; ++r) {
        int c = ct * 32 + lyb + r * 8;
        int m = mt * 32 + lx;
        tile[lyb + r * 8][lx] = X[((size_t)b * 256 + c) * 4096 + m];
    }
    __syncthreads();
#pragma unroll
    for (int r = 0; r < 4; ++r) {
        int m = mt * 32 + lyb + r * 8;
        int c = ct * 32 + lx;
        XT[((size_t)b * 4096 + m) * 256 + c] = tile[lx][lyb + r * 8];
    }
}

// ---------------------------------------------------------------------------
// Fused deformable attention with LDS region staging.
// Block = 256 threads = one (b,g) x 16x4 up-pixel tile (8x2 low-res + halo).
// Region: 6 rows x 11 cols of LR pixels staged in LDS (k: 32ch, x: 64ch).
// Geometry (ty,tx,pix,mask,in-region) precomputed once per (px,pt).
// Out-of-region samples fall back to global loads (rare, always correct).
// ---------------------------------------------------------------------------
#define RROWS 6
#define RCOLS 11
#define RPX   66

__global__ __launch_bounds__(256, 3) void deform_kernel(
    const float* __restrict__ qws,   // [B, 16384, 128] pixel-major
    const float* __restrict__ koff,  // [B, 4096, 416]: n<128 = k, n>=128 = off
    const float* __restrict__ xT,    // [B, 4096, 256] pixel-major
    float* __restrict__ out)         // [B, 256, 128, 128]
{
    __shared__ float sK[RPX * 36];        // staged k rows (pad 36)
    __shared__ float sXr[RPX * 64];       // staged x rows
    __shared__ float sOff[16 * 72];       // offset slice for this (tile, g)
    __shared__ float sQ[64 * 36];         // q rows (pad 36)
    __shared__ float4 sGeo[576];          // {ty, tx, zi, flags} per (px,pt)
    __shared__ float sAttn[576];          // logits -> normalized attn

    int bx = blockIdx.x;
    int tw = bx & 7, th = (bx >> 3) & 31, g = (bx >> 8) & 3, b = bx >> 10;
    int tid = threadIdx.x;
    int wv_ = tid >> 6, lane = tid & 63;

    const size_t kbase = (size_t)b * 4096 * NKOFF;
    const size_t xbase = (size_t)b * 4096 * 256;
    const int ry0 = th * 2 - 2, rx0 = tw * 8 - 1;

    // ---------------- P0: stage region k/x + offsets + q -------------------
    for (int r = 0; r < 10; ++r) {
        int idx = tid + r * 256;
        if (idx < 528) {                       // sK: 66 rows x 8 float4
            int rp = idx >> 3, c4 = idx & 7;
            int qy = rp / RCOLS, qx = rp - qy * RCOLS;
            int gy = min(max(ry0 + qy, 0), 63);
            int gx = min(max(rx0 + qx, 0), 63);
            *(float4*)&sK[rp * 36 + c4 * 4] =
                *(const float4*)&koff[kbase + (size_t)(gy * 64 + gx) * NKOFF +
                                      g * EMB + c4 * 4];
        } else if (idx < 1584) {               // sXr: 66 rows x 16 float4
            int q2 = idx - 528;
            int rp = q2 >> 4, c4 = q2 & 15;
            int qy = rp / RCOLS, qx = rp - qy * RCOLS;
            int gy = min(max(ry0 + qy, 0), 63);
            int gx = min(max(rx0 + qx, 0), 63);
            *(float4*)&sXr[rp * 64 + c4 * 4] =
                *(const float4*)&xT[xbase + (size_t)(gy * 64 + gx) * 256 +
                                    g * CGRP + c4 * 4];
        } else if (idx < 1872) {               // sOff: 16 lr x 18 float4
            int q2 = idx - 1584;
            int lr = q2 / 18, f4 = q2 - (q2 / 18) * 18;
            int yy = th * 2 + (lr >> 3), xx = tw * 8 + (lr & 7);
            *(float4*)&sOff[lr * 72 + f4 * 4] =
                *(const float4*)&koff[kbase + (size_t)(yy * 64 + xx) * NKOFF +
                                      GE + g * 72 + f4 * 4];
        } else if (idx < 2384) {               // sQ: 64 px x 8 float4
            int q2 = idx - 1872;
            int px = q2 >> 3, f4 = q2 & 7;
            int hup = th * 4 + (px >> 4), wup = tw * 16 + (px & 15);
            *(float4*)&sQ[px * 36 + f4 * 4] =
                *(const float4*)&qws[((size_t)b * 16384 + hup * 128 + wup) * GE +
                                     g * EMB + f4 * 4];
        }
    }
    __syncthreads();

    // ---------------- Geo: per (px,pt) geometry -> sGeo --------------------
    for (int item = tid; item < 576; item += 256) {
        int px = item / 9;
        int pt = item - px * 9;
        int lx = px & 15, ly = px >> 4;
        int hup = th * 4 + ly, wup = tw * 16 + lx;
        int lr = (ly >> 1) * 8 + (lx >> 1);
        int ij = ((ly & 1) << 1) | (lx & 1);
        float offy = sOff[lr * 72 + pt * 8 + ij];
        float offx = sOff[lr * 72 + pt * 8 + 4 + ij];
        float py  = offy + hup * 0.5f - 0.25f;
        float pxx = offx + wup * 0.5f - 0.25f;
        float y0f = floorf(py), x0f = floorf(pxx);
        float ty = py - y0f, tx = pxx - x0f;
        int y0 = (int)y0f, x0 = (int)x0f;
        int mk = 0;
        if ((unsigned)y0 < 64u && (unsigned)x0 < 64u) mk |= 1;
        if ((unsigned)y0 < 64u && (unsigned)(x0 + 1) < 64u) mk |= 2;
        if ((unsigned)(y0 + 1) < 64u && (unsigned)x0 < 64u) mk |= 4;
        if ((unsigned)(y0 + 1) < 64u && (unsigned)(x0 + 1) < 64u) mk |= 8;
        int iy = y0 - ry0, ix = x0 - rx0;
        bool inreg = ((unsigned)iy <= (unsigned)(RROWS - 2)) &&
                     ((unsigned)ix <= (unsigned)(RCOLS - 2));
        int zi = inreg ? (iy * RCOLS + ix) : (y0 * 64 + x0);
        int flags = mk | (inreg ? 16 : 0);
        sGeo[item] = make_float4(ty, tx, __int_as_float(zi), __int_as_float(flags));
    }
    __syncthreads();

    // ---------------- Phase A: attention logits ----------------------------
    {
        int s16 = tid >> 4;
        int corner = (tid >> 2) & 3, chunk = tid & 3;
        int dy = corner >> 1, dx = corner & 1;
#pragma unroll 2
        for (int it = 0; it < 36; ++it) {
            int item = it * 16 + s16;
            float4 gg = sGeo[item];
            float ty = gg.x, tx = gg.y;
            int zi = __float_as_int(gg.z);
            int fl = __float_as_int(gg.w);
            float w = (dy ? ty : 1.f - ty) * (dx ? tx : 1.f - tx);
            bool valid = (fl >> corner) & 1;
            float4 k0, k1;
            if (fl & 16) {
                int rp = zi + dy * RCOLS + dx;
                const float4* kr = (const float4*)&sK[rp * 36 + chunk * 8];
                k0 = kr[0]; k1 = kr[1];
            } else {
                int pc = min(max(zi + dy * 64 + dx, 0), 4095);
                const float4* kr = (const float4*)&koff[kbase + (size_t)pc * NKOFF +
                                                        g * EMB + chunk * 8];
                k0 = kr[0]; k1 = kr[1];
            }
            int px = item / 9;
            const float4* qr = (const float4*)&sQ[px * 36 + chunk * 8];
            float4 q0 = qr[0], q1 = qr[1];
            float d = k0.x * q0.x + k0.y * q0.y + k0.z * q0.z + k0.w * q0.w +
                      k1.x * q1.x + k1.y * q1.y + k1.z * q1.z + k1.w * q1.w;
            d = valid ? d * w : 0.f;
            d += __shfl_xor(d, 1);
            d += __shfl_xor(d, 2);
            d += __shfl_xor(d, 4);
            d += __shfl_xor(d, 8);
            if ((tid & 15) == 0) sAttn[item] = d;
        }
    }
    __syncthreads();

    // ---------------- Softmax over 9 points --------------------------------
    if (tid < 64) {
        float a[NPT];
        float mx = -1e30f;
#pragma unroll
        for (int p = 0; p < NPT; ++p) { a[p] = sAttn[tid * 9 + p]; mx = fmaxf(mx, a[p]); }
        float s = 0.f;
#pragma unroll
        for (int p = 0; p < NPT; ++p) { a[p] = __expf(a[p] - mx); s += a[p]; }
        float inv = 1.f / s;
#pragma unroll
        for (int p = 0; p < NPT; ++p) sAttn[tid * 9 + p] = a[p] * inv;
    }
    __syncthreads();

    // ---------------- Phase B: weighted gather of x + direct store ---------
    {
        int pg = lane >> 4, c4 = lane & 15;
        const size_t xch = xbase + g * CGRP + c4 * 4;
#pragma unroll
        for (int sub = 0; sub < 4; ++sub) {
            int px = wv_ * 16 + sub * 4 + pg;
            float ax = 0.f, ay = 0.f, az = 0.f, aw = 0.f;
#pragma unroll 3
            for (int p = 0; p < NPT; ++p) {
                int item = px * 9 + p;
                float4 gg = sGeo[item];
                float ap = sAttn[item];
                float ty = gg.x, tx = gg.y;
                int zi = __float_as_int(gg.z);
                int fl = __float_as_int(gg.w);
                float w00 = (1.f - ty) * (1.f - tx) * ap;
                float w01 = (1.f - ty) * tx * ap;
                float w10 = ty * (1.f - tx) * ap;
                float w11 = ty * tx * ap;
                w00 = (fl & 1) ? w00 : 0.f;
                w01 = (fl & 2) ? w01 : 0.f;
                w10 = (fl & 4) ? w10 : 0.f;
                w11 = (fl & 8) ? w11 : 0.f;
                float4 v0, v1, v2, v3;
                if (fl & 16) {
                    v0 = *(const float4*)&sXr[zi * 64 + c4 * 4];
                    v1 = *(const float4*)&sXr[(zi + 1) * 64 + c4 * 4];
                    v2 = *(const float4*)&sXr[(zi + RCOLS) * 64 + c4 * 4];
                    v3 = *(const float4*)&sXr[(zi + RCOLS + 1) * 64 + c4 * 4];
                } else {
                    int pc0 = min(max(zi, 0), 4095);
                    int pc1 = min(max(zi + 1, 0), 4095);
                    int pc2 = min(max(zi + 64, 0), 4095);
                    int pc3 = min(max(zi + 65, 0), 4095);
                    v0 = *(const float4*)&xT[xch + (size_t)pc0 * 256];
                    v1 = *(const float4*)&xT[xch + (size_t)pc1 * 256];
                    v2 = *(const float4*)&xT[xch + (size_t)pc2 * 256];
                    v3 = *(const float4*)&xT[xch + (size_t)pc3 * 256];
                }
                ax += w00 * v0.x + w01 * v1.x + w10 * v2.x + w11 * v3.x;
                ay += w00 * v0.y + w01 * v1.y + w10 * v2.y + w11 * v3.y;
                az += w00 * v0.z + w01 * v1.z + w10 * v2.z + w11 * v3.z;
                aw += w00 * v0.w + w01 * v1.w + w10 * v2.w + w11 * v3.w;
            }
            int lx = px & 15;
            int hup = th * 4 + wv_, wup = tw * 16 + sub * 4 + pg;
            (void)lx;
            float* ob = out + ((size_t)b * 256 + g * CGRP + c4 * 4) * 16384 +
                        hup * 128 + wup;
            ob[0]     = ax;
            ob[16384] = ay;
            ob[32768] = az;
            ob[49152] = aw;
        }
    }
}

// ---------------------------------------------------------------------------
extern "C" void kernel_launch(void* const* d_in, const int* in_sizes, int n_in,
                              void* d_out, int out_size, void* d_ws, size_t ws_size,
                              hipStream_t stream)
{
    const float* y    = (const float*)d_in[0];
    const float* x    = (const float*)d_in[1];
    const float* Wq   = (const float*)d_in[2];
    const float* bq   = (const float*)d_in[3];
    const float* Wk   = (const float*)d_in[4];
    const float* bk   = (const float*)d_in[5];
    const float* Woff = (const float*)d_in[6];
    const float* boff = (const float*)d_in[7];
    float* out = (float*)d_out;

    float* qws    = (float*)d_ws;
    float* koffws = qws + (size_t)B_N * HUP * WUP * GE;
    float* xTws   = koffws + (size_t)B_N * H_LR * W_LR * NKOFF;

    // q = Wq @ y + bq, pixel-major [B, 16384, 128]
    conv_q_kernel<<<dim3(512), dim3(256), 0, stream>>>(y, Wq, bq, qws);

    // concat(k, off) = [Wk;Woff] @ x + [bk;boff], pixel-major [B, 4096, 416]
    conv1x1_kernel<<<dim3(B_N * 64 * 7), dim3(256), 0, stream>>>(
        x, Wk, bk, Woff, boff, koffws, H_LR * W_LR, NKOFF, GE, 64, 7);

    // xT [B, 4096, 256]
    transpose_kernel<<<dim3(2048), dim3(256), 0, stream>>>(x, xTws);

    // fused deformable attention
    deform_kernel<<<dim3(2048), dim3(256), 0, stream>>>(qws, koffws, xTws, out);
}

// Round 5
// 127.224 us; speedup vs baseline: 2.1812x; 1.4234x over previous
//
#include <hip/hip_runtime.h>

// Problem constants
#define B_N   2
#define H_LR  64
#define W_LR  64
#define HUP   128
#define WUP   128
#define GRP   4
#define NPT   9
#define EMB   32
#define CGRP  64
#define KIN   256
#define GE    128
#define NOFF  288
#define NKOFF 416

typedef __attribute__((ext_vector_type(8))) short short8v;
typedef __attribute__((ext_vector_type(4))) float f32x4;

__device__ __forceinline__ ushort f2bf(float f) {
    unsigned u = __float_as_uint(f);
    u += 0x7FFFu + ((u >> 16) & 1u);
    return (ushort)(u >> 16);
}
__device__ __forceinline__ float bf2f(ushort h) {
    return __uint_as_float(((unsigned)h) << 16);
}

// ---------------------------------------------------------------------------
// conv q: Q[b, m, n] = bq[n] + sum_k Wq[n,k] * Y[b,k,m]; pixel-major out
// ---------------------------------------------------------------------------
__global__ __launch_bounds__(256) void conv_q_kernel(
    const float* __restrict__ Y, const float* __restrict__ Wq,
    const float* __restrict__ bq, float* __restrict__ Q)
{
    __shared__ float sX[32][72];
    __shared__ float sW[32][136];
    int bx = blockIdx.x;
    int mt = bx & 255, b = bx >> 8;
    int m0 = mt * 64;
    int tid = threadIdx.x;
    int tx = tid & 15, ty = tid >> 4;

    float acc[4][8];
#pragma unroll
    for (int i = 0; i < 4; ++i)
#pragma unroll
        for (int j = 0; j < 8; ++j) acc[i][j] = 0.f;

    const float* Yb = Y + (size_t)b * KIN * 16384;

    for (int k0 = 0; k0 < KIN; k0 += 32) {
#pragma unroll
        for (int r = 0; r < 8; ++r) {
            int idx = tid + r * 256;
            int kk = idx >> 6, mm = idx & 63;
            sX[kk][mm] = Yb[(size_t)(k0 + kk) * 16384 + m0 + mm];
        }
#pragma unroll
        for (int r = 0; r < 16; ++r) {
            int idx = tid + r * 256;
            int kk = idx & 31, nn = idx >> 5;
            sW[kk][nn] = Wq[(size_t)nn * KIN + k0 + kk];
        }
        __syncthreads();
#pragma unroll
        for (int kk = 0; kk < 32; ++kk) {
            float xv[4], wv[8];
#pragma unroll
            for (int i = 0; i < 4; ++i) xv[i] = sX[kk][tx * 4 + i];
#pragma unroll
            for (int j = 0; j < 8; ++j) wv[j] = sW[kk][ty * 8 + j];
#pragma unroll
            for (int i = 0; i < 4; ++i)
#pragma unroll
                for (int j = 0; j < 8; ++j) acc[i][j] += xv[i] * wv[j];
        }
        __syncthreads();
    }

    int n = ty * 8;
    float bb[8];
#pragma unroll
    for (int j = 0; j < 8; ++j) bb[j] = bq[n + j];
#pragma unroll
    for (int i = 0; i < 4; ++i) {
        int m = m0 + tx * 4 + i;
        float4 v0, v1;
        v0.x = acc[i][0] + bb[0]; v0.y = acc[i][1] + bb[1];
        v0.z = acc[i][2] + bb[2]; v0.w = acc[i][3] + bb[3];
        v1.x = acc[i][4] + bb[4]; v1.y = acc[i][5] + bb[5];
        v1.z = acc[i][6] + bb[6]; v1.w = acc[i][7] + bb[7];
        *(float4*)&Q[((size_t)b * 16384 + m) * GE + n] = v0;
        *(float4*)&Q[((size_t)b * 16384 + m) * GE + n + 4] = v1;
    }
}

// ---------------------------------------------------------------------------
// concat(k, off) conv GEMM (unchanged)
// ---------------------------------------------------------------------------
__global__ __launch_bounds__(256) void conv1x1_kernel(
    const float* __restrict__ X, const float* __restrict__ W1,
    const float* __restrict__ b1, const float* __restrict__ W2,
    const float* __restrict__ b2, float* __restrict__ C,
    int M, int N, int N1, int mtiles, int ntiles)
{
    __shared__ float sX[32][72];
    __shared__ float sW[32][72];
    int bx = blockIdx.x;
    int mt = bx % mtiles;
    int nt = (bx / mtiles) % ntiles;
    int b  = bx / (mtiles * ntiles);
    int m0 = mt * 64, n0 = nt * 64;
    int tid = threadIdx.x;
    int tx = tid & 15, ty = tid >> 4;

    float acc[4][4];
#pragma unroll
    for (int i = 0; i < 4; ++i)
#pragma unroll
        for (int j = 0; j < 4; ++j) acc[i][j] = 0.f;

    const float* Xb = X + (size_t)b * KIN * M;

    for (int k0 = 0; k0 < KIN; k0 += 32) {
#pragma unroll
        for (int r = 0; r < 8; ++r) {
            int idx = tid + r * 256;
            int kk = idx >> 6, mm = idx & 63;
            sX[kk][mm] = Xb[(size_t)(k0 + kk) * M + m0 + mm];
        }
#pragma unroll
        for (int r = 0; r < 8; ++r) {
            int idx = tid + r * 256;
            int kk = idx & 31, nn = idx >> 5;
            int n = n0 + nn;
            float v = 0.f;
            if (n < N)
                v = (n < N1) ? W1[(size_t)n * KIN + k0 + kk]
                             : W2[(size_t)(n - N1) * KIN + k0 + kk];
            sW[kk][nn] = v;
        }
        __syncthreads();
#pragma unroll
        for (int kk = 0; kk < 32; ++kk) {
            float xv[4], wv[4];
#pragma unroll
            for (int i = 0; i < 4; ++i) xv[i] = sX[kk][tx * 4 + i];
#pragma unroll
            for (int j = 0; j < 4; ++j) wv[j] = sW[kk][ty * 4 + j];
#pragma unroll
            for (int i = 0; i < 4; ++i)
#pragma unroll
                for (int j = 0; j < 4; ++j) acc[i][j] += xv[i] * wv[j];
        }
        __syncthreads();
    }

    int n = n0 + ty * 4;
    if (n < N) {
        float bb[4];
#pragma unroll
        for (int j = 0; j < 4; ++j) {
            int nn = n + j;
            bb[j] = (nn < N1) ? b1[nn] : b2[nn - N1];
        }
#pragma unroll
        for (int i = 0; i < 4; ++i) {
            int m = m0 + tx * 4 + i;
            float4 v;
            v.x = acc[i][0] + bb[0];
            v.y = acc[i][1] + bb[1];
            v.z = acc[i][2] + bb[2];
            v.w = acc[i][3] + bb[3];
            *(float4*)&C[((size_t)b * M + m) * N + n] = v;
        }
    }
}

// ---------------------------------------------------------------------------
// Fused deformable attention via per-block dense MFMA GEMMs.
// Block = 256 thr = one (b,g) x 16x4 up-pixel tile; region = 6x11 LR pixels.
//   S-GEMM : S[64px][66rp] = q . k     (bf16 MFMA, 5 mfma/wave)
//   gather : logits from 4 masked S reads per (px,pt); softmax over 9
//   W-build: W[64px][66rp] += attn*bilinear  (scalar RMW, 64 threads)
//   O-GEMM : out[64px][64ch] = W @ Xregion (bf16 MFMA, 12 mfma/wave)
// Out-of-region samples (~0.7/block): exact global fallback list.
// ---------------------------------------------------------------------------
#define RROWS 6
#define RCOLS 11
#define RPX   66

__global__ __launch_bounds__(256) void deform_kernel(
    const float* __restrict__ qws,   // [B, 16384, 128] pixel-major
    const float* __restrict__ koff,  // [B, 4096, 416]: n<128 = k, n>=128 = off
    const float* __restrict__ x,     // [B, 256, 64, 64] channel-major (input)
    float* __restrict__ out)         // [B, 256, 128, 128]
{
    __shared__ ushort sXt[64][104];   // x region, [ch][rp], cols 66..95 zero
    __shared__ ushort sK[80][40];     // k region bf16 (rows 66..79 junk, unstored)
    __shared__ ushort sQ[64][40];     // q bf16
    __shared__ float  sSW[64][68];    // S table, then reused as W
    __shared__ float2 sGt[576];       // {ty,tx} per (px,pt)
    __shared__ int    sGz[576];       // packed zi + flags
    __shared__ float  sAttn[576];     // logits -> normalized attn
    __shared__ int    sFB[129];       // fallback list (count + items)

    int bx = blockIdx.x;
    int tw = bx & 7, th = (bx >> 3) & 31, g = (bx >> 8) & 3, b = bx >> 10;
    int tid = threadIdx.x;
    int wv_ = tid >> 6, lane = tid & 63;
    int row = lane & 15, kb8 = lane >> 4;

    const size_t kbase = (size_t)b * 4096 * NKOFF;
    const int ry0 = th * 2 - 2, rx0 = tw * 8 - 1;

    // ---------------- P0: memset sXt, stage k/q, geometry ------------------
    if (tid == 0) sFB[0] = 0;
    {
        float4* p = (float4*)&sXt[0][0];
        float4 z4 = make_float4(0.f, 0.f, 0.f, 0.f);
        for (int i = tid; i < 832; i += 256) p[i] = z4;
    }
    for (int i = tid; i < 528; i += 256) {          // sK: 66 rows x 8 quads
        int rp = i >> 3, c4 = i & 7;
        int qy = rp / RCOLS, qx = rp - qy * RCOLS;
        int gy = min(max(ry0 + qy, 0), 63), gx = min(max(rx0 + qx, 0), 63);
        float4 v = *(const float4*)&koff[kbase + (size_t)(gy * 64 + gx) * NKOFF +
                                         g * EMB + c4 * 4];
        ushort4 h;
        h.x = f2bf(v.x); h.y = f2bf(v.y); h.z = f2bf(v.z); h.w = f2bf(v.w);
        *(ushort4*)&sK[rp][c4 * 4] = h;
    }
    for (int i = tid; i < 512; i += 256) {          // sQ: 64 px x 8 quads
        int px = i >> 3, c4 = i & 7;
        int hup = th * 4 + (px >> 4), wup = tw * 16 + (px & 15);
        float4 v = *(const float4*)&qws[((size_t)b * 16384 + hup * 128 + wup) * GE +
                                        g * EMB + c4 * 4];
        ushort4 h;
        h.x = f2bf(v.x); h.y = f2bf(v.y); h.z = f2bf(v.z); h.w = f2bf(v.w);
        *(ushort4*)&sQ[px][c4 * 4] = h;
    }
    for (int item = tid; item < 576; item += 256) { // geometry
        int px = item / 9, pt = item - px * 9;
        int lx = px & 15, ly = px >> 4;
        int hup = th * 4 + ly, wup = tw * 16 + lx;
        int ij = ((hup & 1) << 1) | (wup & 1);
        int pix = (hup >> 1) * 64 + (wup >> 1);
        const float* ob = &koff[kbase + (size_t)pix * NKOFF + GE + (g * 9 + pt) * 8];
        float offy = ob[ij], offx = ob[4 + ij];
        float py  = offy + hup * 0.5f - 0.25f;
        float pxx = offx + wup * 0.5f - 0.25f;
        float y0f = floorf(py), x0f = floorf(pxx);
        float ty = py - y0f, tx = pxx - x0f;
        int y0 = (int)y0f, x0 = (int)x0f;
        int mk = 0;
        if ((unsigned)y0 < 64u && (unsigned)x0 < 64u)       mk |= 1;
        if ((unsigned)y0 < 64u && (unsigned)(x0+1) < 64u)   mk |= 2;
        if ((unsigned)(y0+1) < 64u && (unsigned)x0 < 64u)   mk |= 4;
        if ((unsigned)(y0+1) < 64u && (unsigned)(x0+1) < 64u) mk |= 8;
        int iy = y0 - ry0, ix = x0 - rx0;
        bool inreg = ((unsigned)iy <= (unsigned)(RROWS - 2)) &&
                     ((unsigned)ix <= (unsigned)(RCOLS - 2));
        int fl, zp;
        if (!mk)        { fl = 16; zp = 0; }
        else if (inreg) { fl = mk | 16; zp = iy * RCOLS + ix; }
        else            { fl = mk; zp = (y0 + 1) * 66 + (x0 + 1); }
        sGt[item] = make_float2(ty, tx);
        sGz[item] = (zp << 5) | fl;
    }
    __syncthreads();

    // ---------------- P1: stage x region (transposed) + S-GEMM -------------
    for (int s = tid; s < 384; s += 256) {          // 64 ch x 6 rows
        int ch = s & 63, gy = s >> 6;
        int gyg = min(max(ry0 + gy, 0), 63);
        const float* xr = x + ((size_t)b * 256 + g * CGRP + ch) * 4096 + gyg * 64;
#pragma unroll
        for (int qx = 0; qx < RCOLS; ++qx) {
            int gxg = min(max(rx0 + qx, 0), 63);
            sXt[ch][gy * RCOLS + qx] = f2bf(xr[gxg]);
        }
    }
    {
        short8v a = *(const short8v*)&sQ[wv_ * 16 + row][kb8 * 8];
#pragma unroll
        for (int nt = 0; nt < 5; ++nt) {
            short8v bf = *(const short8v*)&sK[nt * 16 + row][kb8 * 8];
            f32x4 z = {0.f, 0.f, 0.f, 0.f};
            f32x4 d = __builtin_amdgcn_mfma_f32_16x16x32_bf16(a, bf, z, 0, 0, 0);
            int rp = nt * 16 + row;
            if (rp < RPX) {
#pragma unroll
                for (int r = 0; r < 4; ++r)
                    sSW[wv_ * 16 + kb8 * 4 + r][rp] = d[r];
            }
        }
    }
    __syncthreads();

    // ---------------- P2: attention logits ---------------------------------
    for (int item = tid; item < 576; item += 256) {
        int px = item / 9;
        float2 tt = sGt[item];
        int z = sGz[item];
        float ty = tt.x, tx = tt.y;
        int fl = z & 31;
        float a;
        if (fl & 16) {
            int zi = z >> 5;
            float w00 = (1.f - ty) * (1.f - tx), w01 = (1.f - ty) * tx;
            float w10 = ty * (1.f - tx), w11 = ty * tx;
            a  = (fl & 1) ? w00 * sSW[px][zi]            : 0.f;
            a += (fl & 2) ? w01 * sSW[px][zi + 1]        : 0.f;
            a += (fl & 4) ? w10 * sSW[px][zi + RCOLS]    : 0.f;
            a += (fl & 8) ? w11 * sSW[px][zi + RCOLS + 1]: 0.f;
        } else {
            int t = z >> 5;
            int y0 = t / 66 - 1, x0 = t - (t / 66) * 66 - 1;
            a = 0.f;
#pragma unroll
            for (int c = 0; c < 4; ++c) if ((fl >> c) & 1) {
                int dy = c >> 1, dx = c & 1;
                float wgt = (dy ? ty : 1.f - ty) * (dx ? tx : 1.f - tx);
                const float* kr = &koff[kbase + (size_t)((y0 + dy) * 64 + x0 + dx) * NKOFF +
                                        g * EMB];
                float dot = 0.f;
                for (int e = 0; e < EMB; ++e) dot += bf2f(sQ[px][e]) * kr[e];
                a += wgt * dot;
            }
            int old = atomicAdd(&sFB[0], 1);
            if (old < 128) sFB[1 + old] = item;
        }
        sAttn[item] = a;
    }
    __syncthreads();

    // ---------------- P3: softmax (tid<64)  |  zero W (tid>=64) ------------
    if (tid < 64) {
        float aa[NPT];
        float mx = -1e30f;
#pragma unroll
        for (int p = 0; p < NPT; ++p) { aa[p] = sAttn[tid * 9 + p]; mx = fmaxf(mx, aa[p]); }
        float s = 0.f;
#pragma unroll
        for (int p = 0; p < NPT; ++p) { aa[p] = __expf(aa[p] - mx); s += aa[p]; }
        float inv = 1.f / s;
#pragma unroll
        for (int p = 0; p < NPT; ++p) sAttn[tid * 9 + p] = aa[p] * inv;
    } else {
        float4* p = (float4*)&sSW[0][0];
        float4 z4 = make_float4(0.f, 0.f, 0.f, 0.f);
        for (int i = tid - 64; i < 1088; i += 192) p[i] = z4;
    }
    __syncthreads();

    // ---------------- P4: W-build (tid<64, serial RMW) ----------------------
    if (tid < 64) {
        int px = tid;
#pragma unroll
        for (int pt = 0; pt < NPT; ++pt) {
            int item = px * 9 + pt;
            int z = sGz[item];
            int fl = z & 31;
            if (!(fl & 16)) continue;          // fallback items handled in P6
            float2 tt = sGt[item];
            float a = sAttn[item];
            float ty = tt.x, tx = tt.y;
            int zi = z >> 5;
            if (fl & 1) sSW[px][zi]             += (1.f - ty) * (1.f - tx) * a;
            if (fl & 2) sSW[px][zi + 1]         += (1.f - ty) * tx * a;
            if (fl & 4) sSW[px][zi + RCOLS]     += ty * (1.f - tx) * a;
            if (fl & 8) sSW[px][zi + RCOLS + 1] += ty * tx * a;
        }
    }
    __syncthreads();

    // ---------------- P5: out GEMM (W @ Xregion) + store --------------------
    {
        short8v bf[3][4];
#pragma unroll
        for (int kt = 0; kt < 3; ++kt)
#pragma unroll
            for (int nt = 0; nt < 4; ++nt)
                bf[kt][nt] = *(const short8v*)&sXt[nt * 16 + row][kt * 32 + kb8 * 8];

        int px = wv_ * 16 + row;
        short8v af[3];
#pragma unroll
        for (int kt = 0; kt < 2; ++kt) {
            const float* wp = &sSW[px][kt * 32 + kb8 * 8];
            short8v t;
#pragma unroll
            for (int j = 0; j < 8; ++j) t[j] = (short)f2bf(wp[j]);
            af[kt] = t;
        }
        {
            short8v t = {0, 0, 0, 0, 0, 0, 0, 0};
            if (kb8 == 0) {
                const float* wp = &sSW[px][64];
#pragma unroll
                for (int j = 0; j < 4; ++j) t[j] = (short)f2bf(wp[j]);
            }
            af[2] = t;
        }

        f32x4 acc[4];
#pragma unroll
        for (int nt = 0; nt < 4; ++nt) { f32x4 z = {0.f,0.f,0.f,0.f}; acc[nt] = z; }
#pragma unroll
        for (int kt = 0; kt < 3; ++kt)
#pragma unroll
            for (int nt = 0; nt < 4; ++nt)
                acc[nt] = __builtin_amdgcn_mfma_f32_16x16x32_bf16(af[kt], bf[kt][nt],
                                                                  acc[nt], 0, 0, 0);
        int hup = th * 4 + wv_;
#pragma unroll
        for (int nt = 0; nt < 4; ++nt) {
            int ch = nt * 16 + row;
            float* ob = out + ((size_t)b * 256 + g * CGRP + ch) * 16384 +
                        hup * 128 + tw * 16 + kb8 * 4;
#pragma unroll
            for (int r = 0; r < 4; ++r) ob[r] = acc[nt][r];
        }
    }
    __syncthreads();

    // ---------------- P6: rare out-of-region fallback -----------------------
    int nfb = min(sFB[0], 128);
    for (int i = 0; i < nfb; ++i) {
        if (tid < 64) {
            int item = sFB[1 + i];
            int px = item / 9;
            float2 tt = sGt[item];
            int z = sGz[item];
            float a = sAttn[item];
            float ty = tt.x, tx = tt.y;
            int fl = z & 15;
            int t = z >> 5;
            int y0 = t / 66 - 1, x0 = t - (t / 66) * 66 - 1;
            const float* xg = x + ((size_t)b * 256 + g * CGRP + tid) * 4096;
            float v = 0.f;
            if (fl & 1) v += (1.f-ty)*(1.f-tx)*a * xg[y0*64 + x0];
            if (fl & 2) v += (1.f-ty)*tx*a       * xg[y0*64 + x0 + 1];
            if (fl & 4) v += ty*(1.f-tx)*a       * xg[(y0+1)*64 + x0];
            if (fl & 8) v += ty*tx*a             * xg[(y0+1)*64 + x0 + 1];
            int hup = th * 4 + (px >> 4), wup = tw * 16 + (px & 15);
            float* op = out + ((size_t)b * 256 + g * CGRP + tid) * 16384 +
                        hup * 128 + wup;
            *op += v;
        }
    }
}

// ---------------------------------------------------------------------------
extern "C" void kernel_launch(void* const* d_in, const int* in_sizes, int n_in,
                              void* d_out, int out_size, void* d_ws, size_t ws_size,
                              hipStream_t stream)
{
    const float* y    = (const float*)d_in[0];
    const float* x    = (const float*)d_in[1];
    const float* Wq   = (const float*)d_in[2];
    const float* bq   = (const float*)d_in[3];
    const float* Wk   = (const float*)d_in[4];
    const float* bk   = (const float*)d_in[5];
    const float* Woff = (const float*)d_in[6];
    const float* boff = (const float*)d_in[7];
    float* out = (float*)d_out;

    float* qws    = (float*)d_ws;                               // 2*16384*128 floats
    float* koffws = qws + (size_t)B_N * HUP * WUP * GE;         // 2*4096*416 floats

    // q = Wq @ y + bq, pixel-major [B, 16384, 128]
    conv_q_kernel<<<dim3(512), dim3(256), 0, stream>>>(y, Wq, bq, qws);

    // concat(k, off) = [Wk;Woff] @ x + [bk;boff], pixel-major [B, 4096, 416]
    conv1x1_kernel<<<dim3(B_N * 64 * 7), dim3(256), 0, stream>>>(
        x, Wk, bk, Woff, boff, koffws, H_LR * W_LR, NKOFF, GE, 64, 7);

    // fused deformable attention (reads x directly; no transpose pass)
    deform_kernel<<<dim3(2048), dim3(256), 0, stream>>>(qws, koffws, x, out);
}

// Round 7
// 107.498 us; speedup vs baseline: 2.5815x; 1.1835x over previous
//
#include <hip/hip_runtime.h>

// Problem constants
#define B_N   2
#define H_LR  64
#define W_LR  64
#define HUP   128
#define WUP   128
#define GRP   4
#define NPT   9
#define EMB   32
#define CGRP  64
#define KIN   256
#define GE    128
#define NOFF  288

typedef __attribute__((ext_vector_type(8))) short short8v;
typedef __attribute__((ext_vector_type(4))) float f32x4;

__device__ __forceinline__ ushort f2bf(float f) {
    unsigned u = __float_as_uint(f);
    u += 0x7FFFu + ((u >> 16) & 1u);
    return (ushort)(u >> 16);
}
__device__ __forceinline__ float bf2f(ushort h) {
    return __uint_as_float(((unsigned)h) << 16);
}

// ---------------------------------------------------------------------------
// Weight conversion: Wq -> wqbf [128][256]; [Wk;Woff;0] -> wkobf [512][256]
// ---------------------------------------------------------------------------
__global__ __launch_bounds__(256) void convert_w_kernel(
    const float* __restrict__ Wq, const float* __restrict__ Wk,
    const float* __restrict__ Woff, ushort* __restrict__ wqbf,
    ushort* __restrict__ wkobf)
{
    int r = blockIdx.x, k = threadIdx.x;
    if (r < 128) {
        wqbf[r * 256 + k] = f2bf(Wq[r * 256 + k]);
    } else {
        int r2 = r - 128;
        float v = 0.f;
        if (r2 < 128) v = Wk[r2 * 256 + k];
        else if (r2 < 416) v = Woff[(r2 - 128) * 256 + k];
        wkobf[r2 * 256 + k] = f2bf(v);
    }
}

// ---------------------------------------------------------------------------
// bf16 MFMA GEMM for 1x1 convs.
// C[b, m, n] = bias[n] + sum_k W[n,k] * SRC[b, k, m]
// BM=128, BN=128, BK=64. 256 threads = 4 waves (2m x 2n), 64x64 per wave.
// SRC fp32 staged [k][m] in LDS (pad 133); A-frags via transposed scalar
// reads + f2bf. WBF bf16 [n][k] staged for direct b128 frag reads.
// Epilogue: n<128 -> bf16 OBF (stride 128); n>=128 -> fp32 OFP (stride 288).
// ---------------------------------------------------------------------------
__global__ __launch_bounds__(256) void mfma_gemm(
    const float* __restrict__ SRC, const ushort* __restrict__ WBF,
    const float* __restrict__ bias_a, const float* __restrict__ bias_b,
    ushort* __restrict__ OBF, float* __restrict__ OFP,
    int M, int mtiles, int ntiles)
{
    __shared__ float  sY[64][133];
    __shared__ ushort sB[128][72];

    int bx = blockIdx.x;
    int mt = bx % mtiles;
    int nt = (bx / mtiles) % ntiles;
    int b  = bx / (mtiles * ntiles);
    int m0 = mt * 128, n0 = nt * 128;
    int tid = threadIdx.x;
    int lane = tid & 63;
    int wv = tid >> 6, wm = wv >> 1, wn = wv & 1;
    int il = lane & 15, g4 = lane >> 4;

    f32x4 acc[4][4];
#pragma unroll
    for (int i = 0; i < 4; ++i)
#pragma unroll
        for (int j = 0; j < 4; ++j) { f32x4 z = {0.f,0.f,0.f,0.f}; acc[i][j] = z; }

    const float* src_b = SRC + (size_t)b * KIN * M;

    for (int k0 = 0; k0 < KIN; k0 += 64) {
        // stage activation tile: 64 k-rows x 128 m, fp32 (coalesced global)
#pragma unroll
        for (int i = 0; i < 8; ++i) {
            int idx = tid + i * 256;
            int m4 = idx & 31, c = idx >> 5;
            float4 v = *(const float4*)&src_b[(size_t)(k0 + c) * M + m0 + m4 * 4];
            float* d = &sY[c][m4 * 4];
            d[0] = v.x; d[1] = v.y; d[2] = v.z; d[3] = v.w;
        }
        // stage weight tile: 128 n x 64 k bf16 (direct copy)
#pragma unroll
        for (int i = 0; i < 4; ++i) {
            int idx = tid + i * 256;
            int c8 = idx & 7, n = idx >> 3;
            *(short8v*)&sB[n][c8 * 8] =
                *(const short8v*)&WBF[(size_t)(n0 + n) * KIN + k0 + c8 * 8];
        }
        __syncthreads();
#pragma unroll
        for (int kc = 0; kc < 2; ++kc) {
            short8v af[4], bfr[4];
            int kb = kc * 32 + g4 * 8;
#pragma unroll
            for (int mf = 0; mf < 4; ++mf) {
                int m = wm * 64 + mf * 16 + il;
                short8v t;
#pragma unroll
                for (int j = 0; j < 8; ++j) t[j] = (short)f2bf(sY[kb + j][m]);
                af[mf] = t;
            }
#pragma unroll
            for (int nf = 0; nf < 4; ++nf) {
                int n = wn * 64 + nf * 16 + il;
                bfr[nf] = *(const short8v*)&sB[n][kc * 32 + g4 * 8];
            }
#pragma unroll
            for (int mf = 0; mf < 4; ++mf)
#pragma unroll
                for (int nf = 0; nf < 4; ++nf)
                    acc[mf][nf] = __builtin_amdgcn_mfma_f32_16x16x32_bf16(
                        af[mf], bfr[nf], acc[mf][nf], 0, 0, 0);
        }
        __syncthreads();
    }

    // epilogue
#pragma unroll
    for (int mf = 0; mf < 4; ++mf) {
#pragma unroll
        for (int r = 0; r < 4; ++r) {
            int m = m0 + wm * 64 + mf * 16 + g4 * 4 + r;
            size_t row = (size_t)b * M + m;
#pragma unroll
            for (int nf = 0; nf < 4; ++nf) {
                int nl = wn * 64 + nf * 16 + il;
                int n  = n0 + nl;
                float v = acc[mf][nf][r];
                if (n < GE) {
                    OBF[row * 128 + n] = f2bf(v + bias_a[n]);
                } else {
                    int no = n - GE;
                    if (no < NOFF) OFP[row * 288 + no] = v + bias_b[no];
                }
            }
        }
    }
}

// ---------------------------------------------------------------------------
// Fused deformable attention via per-block dense MFMA GEMMs.
// ---------------------------------------------------------------------------
#define RROWS 6
#define RCOLS 11
#define RPX   66

__global__ __launch_bounds__(256) void deform_kernel(
    const ushort* __restrict__ qbf,  // [B, 16384, 128] bf16 pixel-major
    const ushort* __restrict__ kbf,  // [B, 4096, 128] bf16 pixel-major
    const float* __restrict__ offw,  // [B, 4096, 288] fp32 pixel-major
    const float* __restrict__ x,     // [B, 256, 64, 64] channel-major (input)
    float* __restrict__ out)         // [B, 256, 128, 128]
{
    __shared__ ushort sXt[64][104];   // x region, [ch][rp], cols 66..95 zero
    __shared__ ushort sK[80][40];     // k region bf16
    __shared__ ushort sQ[64][40];     // q bf16
    __shared__ float  sSW[64][68];    // S table, then reused as W
    __shared__ float2 sGt[576];       // {ty,tx} per (px,pt)
    __shared__ int    sGz[576];       // packed zi + flags
    __shared__ float  sAttn[576];     // logits -> normalized attn
    __shared__ int    sFB[129];       // fallback list (count + items)

    int bx = blockIdx.x;
    int tw = bx & 7, th = (bx >> 3) & 31, g = (bx >> 8) & 3, b = bx >> 10;
    int tid = threadIdx.x;
    int wv_ = tid >> 6, lane = tid & 63;
    int row = lane & 15, kb8 = lane >> 4;

    const int ry0 = th * 2 - 2, rx0 = tw * 8 - 1;

    // ---------------- P0: memset sXt, stage k/q, geometry ------------------
    if (tid == 0) sFB[0] = 0;
    {
        float4* p = (float4*)&sXt[0][0];
        float4 z4 = make_float4(0.f, 0.f, 0.f, 0.f);
        for (int i = tid; i < 832; i += 256) p[i] = z4;
    }
    for (int i = tid; i < 264; i += 256) {          // sK: 66 rows x 4 chunks
        int rp = i >> 2, c4 = i & 3;
        int qy = rp / RCOLS, qx = rp - qy * RCOLS;
        int gy = min(max(ry0 + qy, 0), 63), gx = min(max(rx0 + qx, 0), 63);
        *(short8v*)&sK[rp][c4 * 8] =
            *(const short8v*)&kbf[((size_t)b * 4096 + gy * 64 + gx) * 128 +
                                  g * EMB + c4 * 8];
    }
    {                                                // sQ: 64 px x 4 chunks
        int px = tid >> 2, c4 = tid & 3;
        int hup = th * 4 + (px >> 4), wup = tw * 16 + (px & 15);
        *(short8v*)&sQ[px][c4 * 8] =
            *(const short8v*)&qbf[((size_t)b * 16384 + hup * 128 + wup) * 128 +
                                  g * EMB + c4 * 8];
    }
    for (int item = tid; item < 576; item += 256) { // geometry
        int px = item / 9, pt = item - px * 9;
        int lx = px & 15, ly = px >> 4;
        int hup = th * 4 + ly, wup = tw * 16 + lx;
        int ij = ((hup & 1) << 1) | (wup & 1);
        int pix = (hup >> 1) * 64 + (wup >> 1);
        const float* ob = &offw[((size_t)b * 4096 + pix) * 288 + (g * 9 + pt) * 8];
        float offy = ob[ij], offx = ob[4 + ij];
        float py  = offy + hup * 0.5f - 0.25f;
        float pxx = offx + wup * 0.5f - 0.25f;
        float y0f = floorf(py), x0f = floorf(pxx);
        float ty = py - y0f, tx = pxx - x0f;
        int y0 = (int)y0f, x0 = (int)x0f;
        int mk = 0;
        if ((unsigned)y0 < 64u && (unsigned)x0 < 64u)       mk |= 1;
        if ((unsigned)y0 < 64u && (unsigned)(x0+1) < 64u)   mk |= 2;
        if ((unsigned)(y0+1) < 64u && (unsigned)x0 < 64u)   mk |= 4;
        if ((unsigned)(y0+1) < 64u && (unsigned)(x0+1) < 64u) mk |= 8;
        int iy = y0 - ry0, ix = x0 - rx0;
        bool inreg = ((unsigned)iy <= (unsigned)(RROWS - 2)) &&
                     ((unsigned)ix <= (unsigned)(RCOLS - 2));
        int fl, zp;
        if (!mk)        { fl = 16; zp = 0; }
        else if (inreg) { fl = mk | 16; zp = iy * RCOLS + ix; }
        else            { fl = mk; zp = (y0 + 1) * 66 + (x0 + 1); }
        sGt[item] = make_float2(ty, tx);
        sGz[item] = (zp << 5) | fl;
    }
    __syncthreads();

    // ---------------- P1: stage x region (transposed) + S-GEMM -------------
    for (int s = tid; s < 384; s += 256) {          // 64 ch x 6 rows
        int ch = s & 63, gy = s >> 6;
        int gyg = min(max(ry0 + gy, 0), 63);
        const float* xr = x + ((size_t)b * 256 + g * CGRP + ch) * 4096 + gyg * 64;
#pragma unroll
        for (int qx = 0; qx < RCOLS; ++qx) {
            int gxg = min(max(rx0 + qx, 0), 63);
            sXt[ch][gy * RCOLS + qx] = f2bf(xr[gxg]);
        }
    }
    {
        short8v a = *(const short8v*)&sQ[wv_ * 16 + row][kb8 * 8];
#pragma unroll
        for (int nt = 0; nt < 5; ++nt) {
            short8v bf = *(const short8v*)&sK[nt * 16 + row][kb8 * 8];
            f32x4 z = {0.f, 0.f, 0.f, 0.f};
            f32x4 d = __builtin_amdgcn_mfma_f32_16x16x32_bf16(a, bf, z, 0, 0, 0);
            int rp = nt * 16 + row;
            if (rp < RPX) {
#pragma unroll
                for (int r = 0; r < 4; ++r)
                    sSW[wv_ * 16 + kb8 * 4 + r][rp] = d[r];
            }
        }
    }
    __syncthreads();

    // ---------------- P2: attention logits ---------------------------------
    for (int item = tid; item < 576; item += 256) {
        int px = item / 9;
        float2 tt = sGt[item];
        int z = sGz[item];
        float ty = tt.x, tx = tt.y;
        int fl = z & 31;
        float a;
        if (fl & 16) {
            int zi = z >> 5;
            float w00 = (1.f - ty) * (1.f - tx), w01 = (1.f - ty) * tx;
            float w10 = ty * (1.f - tx), w11 = ty * tx;
            a  = (fl & 1) ? w00 * sSW[px][zi]            : 0.f;
            a += (fl & 2) ? w01 * sSW[px][zi + 1]        : 0.f;
            a += (fl & 4) ? w10 * sSW[px][zi + RCOLS]    : 0.f;
            a += (fl & 8) ? w11 * sSW[px][zi + RCOLS + 1]: 0.f;
        } else {
            int t = z >> 5;
            int y0 = t / 66 - 1, x0 = t - (t / 66) * 66 - 1;
            a = 0.f;
#pragma unroll
            for (int c = 0; c < 4; ++c) if ((fl >> c) & 1) {
                int dy = c >> 1, dx = c & 1;
                float wgt = (dy ? ty : 1.f - ty) * (dx ? tx : 1.f - tx);
                const ushort* kr = &kbf[((size_t)b * 4096 + (y0 + dy) * 64 + x0 + dx) * 128 +
                                        g * EMB];
                float dot = 0.f;
                for (int e = 0; e < EMB; ++e) dot += bf2f(sQ[px][e]) * bf2f(kr[e]);
                a += wgt * dot;
            }
            int old = atomicAdd(&sFB[0], 1);
            if (old < 128) sFB[1 + old] = item;
        }
        sAttn[item] = a;
    }
    __syncthreads();

    // ---------------- P3: softmax (tid<64)  |  zero W (tid>=64) ------------
    if (tid < 64) {
        float aa[NPT];
        float mx = -1e30f;
#pragma unroll
        for (int p = 0; p < NPT; ++p) { aa[p] = sAttn[tid * 9 + p]; mx = fmaxf(mx, aa[p]); }
        float s = 0.f;
#pragma unroll
        for (int p = 0; p < NPT; ++p) { aa[p] = __expf(aa[p] - mx); s += aa[p]; }
        float inv = 1.f / s;
#pragma unroll
        for (int p = 0; p < NPT; ++p) sAttn[tid * 9 + p] = aa[p] * inv;
    } else {
        float4* p = (float4*)&sSW[0][0];
        float4 z4 = make_float4(0.f, 0.f, 0.f, 0.f);
        for (int i = tid - 64; i < 1088; i += 192) p[i] = z4;
    }
    __syncthreads();

    // ---------------- P4: W-build (tid<64, serial RMW) ----------------------
    if (tid < 64) {
        int px = tid;
#pragma unroll
        for (int pt = 0; pt < NPT; ++pt) {
            int item = px * 9 + pt;
            int z = sGz[item];
            int fl = z & 31;
            if (!(fl & 16)) continue;          // fallback items handled in P6
            float2 tt = sGt[item];
            float a = sAttn[item];
            float ty = tt.x, tx = tt.y;
            int zi = z >> 5;
            if (fl & 1) sSW[px][zi]             += (1.f - ty) * (1.f - tx) * a;
            if (fl & 2) sSW[px][zi + 1]         += (1.f - ty) * tx * a;
            if (fl & 4) sSW[px][zi + RCOLS]     += ty * (1.f - tx) * a;
            if (fl & 8) sSW[px][zi + RCOLS + 1] += ty * tx * a;
        }
    }
    __syncthreads();

    // ---------------- P5: out GEMM (W @ Xregion) + store --------------------
    {
        short8v bf[3][4];
#pragma unroll
        for (int kt = 0; kt < 3; ++kt)
#pragma unroll
            for (int nt = 0; nt < 4; ++nt)
                bf[kt][nt] = *(const short8v*)&sXt[nt * 16 + row][kt * 32 + kb8 * 8];

        int px = wv_ * 16 + row;
        short8v af[3];
#pragma unroll
        for (int kt = 0; kt < 2; ++kt) {
            const float* wp = &sSW[px][kt * 32 + kb8 * 8];
            short8v t;
#pragma unroll
            for (int j = 0; j < 8; ++j) t[j] = (short)f2bf(wp[j]);
            af[kt] = t;
        }
        {
            short8v t = {0, 0, 0, 0, 0, 0, 0, 0};
            if (kb8 == 0) {
                const float* wp = &sSW[px][64];
#pragma unroll
                for (int j = 0; j < 4; ++j) t[j] = (short)f2bf(wp[j]);
            }
            af[2] = t;
        }

        f32x4 acc[4];
#pragma unroll
        for (int nt = 0; nt < 4; ++nt) { f32x4 z = {0.f,0.f,0.f,0.f}; acc[nt] = z; }
#pragma unroll
        for (int kt = 0; kt < 3; ++kt)
#pragma unroll
            for (int nt = 0; nt < 4; ++nt)
                acc[nt] = __builtin_amdgcn_mfma_f32_16x16x32_bf16(af[kt], bf[kt][nt],
                                                                  acc[nt], 0, 0, 0);
        int hup = th * 4 + wv_;
#pragma unroll
        for (int nt = 0; nt < 4; ++nt) {
            int ch = nt * 16 + row;
            float* ob = out + ((size_t)b * 256 + g * CGRP + ch) * 16384 +
                        hup * 128 + tw * 16 + kb8 * 4;
#pragma unroll
            for (int r = 0; r < 4; ++r) ob[r] = acc[nt][r];
        }
    }
    __syncthreads();

    // ---------------- P6: rare out-of-region fallback -----------------------
    int nfb = min(sFB[0], 128);
    for (int i = 0; i < nfb; ++i) {
        if (tid < 64) {
            int item = sFB[1 + i];
            int px = item / 9;
            float2 tt = sGt[item];
            int z = sGz[item];
            float a = sAttn[item];
            float ty = tt.x, tx = tt.y;
            int fl = z & 15;
            int t = z >> 5;
            int y0 = t / 66 - 1, x0 = t - (t / 66) * 66 - 1;
            const float* xg = x + ((size_t)b * 256 + g * CGRP + tid) * 4096;
            float v = 0.f;
            if (fl & 1) v += (1.f-ty)*(1.f-tx)*a * xg[y0*64 + x0];
            if (fl & 2) v += (1.f-ty)*tx*a       * xg[y0*64 + x0 + 1];
            if (fl & 4) v += ty*(1.f-tx)*a       * xg[(y0+1)*64 + x0];
            if (fl & 8) v += ty*tx*a             * xg[(y0+1)*64 + x0 + 1];
            int hup = th * 4 + (px >> 4), wup = tw * 16 + (px & 15);
            float* op = out + ((size_t)b * 256 + g * CGRP + tid) * 16384 +
                        hup * 128 + wup;
            *op += v;
        }
    }
}

// ---------------------------------------------------------------------------
extern "C" void kernel_launch(void* const* d_in, const int* in_sizes, int n_in,
                              void* d_out, int out_size, void* d_ws, size_t ws_size,
                              hipStream_t stream)
{
    const float* y    = (const float*)d_in[0];
    const float* x    = (const float*)d_in[1];
    const float* Wq   = (const float*)d_in[2];
    const float* bq   = (const float*)d_in[3];
    const float* Wk   = (const float*)d_in[4];
    const float* bk   = (const float*)d_in[5];
    const float* Woff = (const float*)d_in[6];
    const float* boff = (const float*)d_in[7];
    float* out = (float*)d_out;

    // workspace layout (20.3 MB total)
    ushort* wqbf  = (ushort*)d_ws;                          // 128*256
    ushort* wkobf = wqbf + 128 * 256;                       // 512*256
    ushort* qbf   = wkobf + 512 * 256;                      // 2*16384*128
    ushort* kbf   = qbf + (size_t)B_N * 16384 * 128;        // 2*4096*128
    float*  offw  = (float*)(kbf + (size_t)B_N * 4096 * 128); // 2*4096*288

    // weights -> bf16 (zero-padded koff rows 416..511)
    convert_w_kernel<<<dim3(640), dim3(256), 0, stream>>>(Wq, Wk, Woff, wqbf, wkobf);

    // q = Wq @ y + bq  -> bf16 [B,16384,128]
    mfma_gemm<<<dim3(256), dim3(256), 0, stream>>>(
        y, wqbf, bq, nullptr, qbf, nullptr, 16384, 128, 1);

    // [k;off] = [Wk;Woff] @ x + [bk;boff] -> k bf16 [B,4096,128], off fp32 [B,4096,288]
    mfma_gemm<<<dim3(256), dim3(256), 0, stream>>>(
        x, wkobf, bk, boff, kbf, offw, 4096, 32, 4);

    // fused deformable attention
    deform_kernel<<<dim3(2048), dim3(256), 0, stream>>>(qbf, kbf, offw, x, out);
}

// Round 8
// 78.870 us; speedup vs baseline: 3.5185x; 1.3630x over previous
//
#include <hip/hip_runtime.h>

// Problem constants
#define B_N   2
#define H_LR  64
#define W_LR  64
#define HUP   128
#define WUP   128
#define GRP   4
#define NPT   9
#define EMB   32
#define CGRP  64
#define KIN   256
#define GE    128
#define NOFF  288

typedef __attribute__((ext_vector_type(8))) short short8v;
typedef _Float16 half8v __attribute__((ext_vector_type(8)));
typedef __attribute__((ext_vector_type(4))) float f32x4;

__device__ __forceinline__ ushort f2bf(float f) {
    unsigned u = __float_as_uint(f);
    u += 0x7FFFu + ((u >> 16) & 1u);
    return (ushort)(u >> 16);
}
__device__ __forceinline__ float bf2f(ushort h) {
    return __uint_as_float(((unsigned)h) << 16);
}
__device__ __forceinline__ ushort f2h(float f) {
    _Float16 h = (_Float16)f;
    return __builtin_bit_cast(ushort, h);
}
__device__ __forceinline__ float h2f(ushort u) {
    _Float16 h = __builtin_bit_cast(_Float16, u);
    return (float)h;
}

// ---------------------------------------------------------------------------
// Weight conversion: Wq -> wqbf [128][256]; [Wk;Woff;0] -> wkobf [512][256]
// ---------------------------------------------------------------------------
__global__ __launch_bounds__(256) void convert_w_kernel(
    const float* __restrict__ Wq, const float* __restrict__ Wk,
    const float* __restrict__ Woff, ushort* __restrict__ wqbf,
    ushort* __restrict__ wkobf)
{
    int r = blockIdx.x, k = threadIdx.x;
    if (r < 128) {
        wqbf[r * 256 + k] = f2bf(Wq[r * 256 + k]);
    } else {
        int r2 = r - 128;
        float v = 0.f;
        if (r2 < 128) v = Wk[r2 * 256 + k];
        else if (r2 < 416) v = Woff[(r2 - 128) * 256 + k];
        wkobf[r2 * 256 + k] = f2bf(v);
    }
}

// ---------------------------------------------------------------------------
// bf16 MFMA GEMM for 1x1 convs.  C[b,m,n] = bias[n] + sum_k W[n,k]*SRC[b,k,m]
// BM=64, BN=128, BK=64. 256 thr = 4 waves (2m x 2n), each 32x64.
// SRC fp32 -> bf16 at stage time, LDS [k][m] pad 68; A-frag = 8 ds_read_u16.
// Weights bf16 [n][k] pad 72, direct b128 frag reads.
// Epilogue: n<128 -> bf16 OBF (stride 128); 128<=n<416 -> fp32 OFP (stride 288).
// ---------------------------------------------------------------------------
__global__ __launch_bounds__(256, 4) void mfma_gemm(
    const float* __restrict__ SRC, const ushort* __restrict__ WBF,
    const float* __restrict__ bias_a, const float* __restrict__ bias_b,
    ushort* __restrict__ OBF, float* __restrict__ OFP,
    int M, int mtiles, int ntiles)
{
    __shared__ __align__(16) ushort sY[64][68];
    __shared__ __align__(16) ushort sB[128][72];

    int bx = blockIdx.x;
    int mt = bx % mtiles;
    int nt = (bx / mtiles) % ntiles;
    int b  = bx / (mtiles * ntiles);
    int m0 = mt * 64, n0 = nt * 128;
    int tid = threadIdx.x;
    int lane = tid & 63;
    int wv = tid >> 6, wm = wv >> 1, wn = wv & 1;
    int il = lane & 15, g4 = lane >> 4;

    f32x4 acc[2][4];
#pragma unroll
    for (int i = 0; i < 2; ++i)
#pragma unroll
        for (int j = 0; j < 4; ++j) { f32x4 z = {0.f,0.f,0.f,0.f}; acc[i][j] = z; }

    const float* src_b = SRC + (size_t)b * KIN * M;

    for (int k0 = 0; k0 < KIN; k0 += 64) {
        // stage activations: 64 k x 64 m fp32 -> bf16 (coalesced float4)
#pragma unroll
        for (int i = 0; i < 4; ++i) {
            int idx = tid + i * 256;
            int m4 = idx & 15, c = idx >> 4;
            float4 v = *(const float4*)&src_b[(size_t)(k0 + c) * M + m0 + m4 * 4];
            ushort4 h;
            h.x = f2bf(v.x); h.y = f2bf(v.y); h.z = f2bf(v.z); h.w = f2bf(v.w);
            *(ushort4*)&sY[c][m4 * 4] = h;
        }
        // stage weights: 128 n x 64 k bf16 (direct copy)
#pragma unroll
        for (int i = 0; i < 4; ++i) {
            int idx = tid + i * 256;
            int c8 = idx & 7, n = idx >> 3;
            *(short8v*)&sB[n][c8 * 8] =
                *(const short8v*)&WBF[(size_t)(n0 + n) * KIN + k0 + c8 * 8];
        }
        __syncthreads();
#pragma unroll
        for (int kc = 0; kc < 2; ++kc) {
            int kb = kc * 32 + g4 * 8;
            short8v af[2], bfr[4];
#pragma unroll
            for (int mf = 0; mf < 2; ++mf) {
                int m = wm * 32 + mf * 16 + il;
                short8v t;
#pragma unroll
                for (int j = 0; j < 8; ++j) t[j] = (short)sY[kb + j][m];
                af[mf] = t;
            }
#pragma unroll
            for (int nf = 0; nf < 4; ++nf)
                bfr[nf] = *(const short8v*)&sB[wn * 64 + nf * 16 + il][kb];
#pragma unroll
            for (int mf = 0; mf < 2; ++mf)
#pragma unroll
                for (int nf = 0; nf < 4; ++nf)
                    acc[mf][nf] = __builtin_amdgcn_mfma_f32_16x16x32_bf16(
                        af[mf], bfr[nf], acc[mf][nf], 0, 0, 0);
        }
        __syncthreads();
    }

    // epilogue
#pragma unroll
    for (int mf = 0; mf < 2; ++mf) {
#pragma unroll
        for (int r = 0; r < 4; ++r) {
            int m = m0 + wm * 32 + mf * 16 + g4 * 4 + r;
            size_t row = (size_t)b * M + m;
#pragma unroll
            for (int nf = 0; nf < 4; ++nf) {
                int n = n0 + wn * 64 + nf * 16 + il;
                float v = acc[mf][nf][r];
                if (n < GE) {
                    OBF[row * 128 + n] = f2bf(v + bias_a[n]);
                } else {
                    int no = n - GE;
                    if (no < NOFF) OFP[row * 288 + no] = v + bias_b[no];
                }
            }
        }
    }
}

// ---------------------------------------------------------------------------
// Fused deformable attention via per-block dense MFMA GEMMs.
// Block = 256 thr = one (b,g) x 16x4 up-pixel tile; region = 6x11 LR pixels.
// LDS 39.3 KB -> 4 blocks/CU.  S/W and x-region in fp16; O-GEMM uses f16 MFMA.
// Offsets staged coalesced into LDS (aliases sSW before S is live).
// ---------------------------------------------------------------------------
#define RROWS 6
#define RCOLS 11
#define RPX   66

__global__ __launch_bounds__(256, 4) void deform_kernel(
    const ushort* __restrict__ qbf,  // [B, 16384, 128] bf16 pixel-major
    const ushort* __restrict__ kbf,  // [B, 4096, 128] bf16 pixel-major
    const float* __restrict__ offw,  // [B, 4096, 288] fp32 pixel-major
    const float* __restrict__ x,     // [B, 256, 64, 64] channel-major (input)
    float* __restrict__ out)         // [B, 256, 128, 128]
{
    __shared__ __align__(16) ushort sXt[64][96];  // x region fp16 [ch][rp], 66..95 zero
    __shared__ __align__(16) ushort sK[66][40];   // k region bf16
    __shared__ __align__(16) ushort sQ[64][40];   // q bf16
    __shared__ __align__(16) ushort sSW[64][72];  // P0: sOff fp32; P1+: S then W fp16
    __shared__ uint   sGt[576];                   // packed {ty,tx} fp16
    __shared__ int    sGz[576];                   // packed zi + flags
    __shared__ float  sAttn[576];                 // logits -> normalized attn
    __shared__ int    sFB[129];                   // fallback list

    int bx = blockIdx.x;
    int tw = bx & 7, th = (bx >> 3) & 31, g = (bx >> 8) & 3, b = bx >> 10;
    int tid = threadIdx.x;
    int wv_ = tid >> 6, lane = tid & 63;
    int row = lane & 15, kb8 = lane >> 4;

    const int ry0 = th * 2 - 2, rx0 = tw * 8 - 1;
    float* sOff = (float*)&sSW[0][0];             // [16][72] fp32 (4.6 KB of 9.2)

    // ---------------- P0a: all staging (coalesced) -------------------------
    if (tid == 0) sFB[0] = 0;
    // zero sXt pad cols 66..95 (data cols 0..65 fully overwritten below)
    for (int i = tid; i < 960; i += 256) {
        int r = i / 15, j = i - (i / 15) * 15;
        *(uint*)&sXt[r][66 + j * 2] = 0;
    }
    // x region -> fp16 (gy-major lane map; interior tiles use float4 loads)
    for (int s = tid; s < 384; s += 256) {
        int gy = s % 6, ch = s / 6;
        int gyg = min(max(ry0 + gy, 0), 63);
        const float* xr = x + ((size_t)b * 256 + g * CGRP + ch) * 4096 + gyg * 64;
        ushort* dst = &sXt[ch][gy * RCOLS];
        if (tw >= 1 && tw <= 6) {
            int a0 = rx0 - 3;                    // 16B-aligned, in-bounds
            float v[16];
#pragma unroll
            for (int t4 = 0; t4 < 4; ++t4) {
                float4 f = *(const float4*)&xr[a0 + t4 * 4];
                v[t4*4+0] = f.x; v[t4*4+1] = f.y; v[t4*4+2] = f.z; v[t4*4+3] = f.w;
            }
#pragma unroll
            for (int qx = 0; qx < RCOLS; ++qx) dst[qx] = f2h(v[qx + 3]);
        } else {
#pragma unroll
            for (int qx = 0; qx < RCOLS; ++qx) {
                int gxg = min(max(rx0 + qx, 0), 63);
                dst[qx] = f2h(xr[gxg]);
            }
        }
    }
    // k region bf16
    for (int i = tid; i < 264; i += 256) {
        int rp = i >> 2, c4 = i & 3;
        int qy = rp / RCOLS, qx = rp - qy * RCOLS;
        int gy = min(max(ry0 + qy, 0), 63), gx = min(max(rx0 + qx, 0), 63);
        *(short8v*)&sK[rp][c4 * 8] =
            *(const short8v*)&kbf[((size_t)b * 4096 + gy * 64 + gx) * 128 +
                                  g * EMB + c4 * 8];
    }
    // q bf16
    {
        int px = tid >> 2, c4 = tid & 3;
        int hup = th * 4 + (px >> 4), wup = tw * 16 + (px & 15);
        *(short8v*)&sQ[px][c4 * 8] =
            *(const short8v*)&qbf[((size_t)b * 16384 + hup * 128 + wup) * 128 +
                                  g * EMB + c4 * 8];
    }
    // offsets (coalesced float4) -> sOff
    for (int i = tid; i < 288; i += 256) {
        int lr = i / 18, f4 = i - (i / 18) * 18;
        int yy = th * 2 + (lr >> 3), xx = tw * 8 + (lr & 7);
        *(float4*)&sOff[lr * 72 + f4 * 4] =
            *(const float4*)&offw[((size_t)b * 4096 + yy * 64 + xx) * 288 +
                                  g * 72 + f4 * 4];
    }
    __syncthreads();

    // ---------------- P0b: S-GEMM (to regs) + geometry ---------------------
    f32x4 sreg[5];
    {
        short8v a = *(const short8v*)&sQ[wv_ * 16 + row][kb8 * 8];
#pragma unroll
        for (int nt = 0; nt < 5; ++nt) {
            int rr = nt * 16 + row; if (rr > 65) rr = 65;   // tail clamp
            short8v bf = *(const short8v*)&sK[rr][kb8 * 8];
            f32x4 z = {0.f, 0.f, 0.f, 0.f};
            sreg[nt] = __builtin_amdgcn_mfma_f32_16x16x32_bf16(a, bf, z, 0, 0, 0);
        }
    }
    for (int item = tid; item < 576; item += 256) {
        int px = item / 9, pt = item - (item / 9) * 9;
        int lx = px & 15, ly = px >> 4;
        int hup = th * 4 + ly, wup = tw * 16 + lx;
        int lr = (ly >> 1) * 8 + (lx >> 1);
        int ij = ((hup & 1) << 1) | (wup & 1);
        float offy = sOff[lr * 72 + pt * 8 + ij];
        float offx = sOff[lr * 72 + pt * 8 + 4 + ij];
        float py  = offy + hup * 0.5f - 0.25f;
        float pxx = offx + wup * 0.5f - 0.25f;
        float y0f = floorf(py), x0f = floorf(pxx);
        float ty = py - y0f, tx = pxx - x0f;
        int y0 = (int)y0f, x0 = (int)x0f;
        int mk = 0;
        if ((unsigned)y0 < 64u && (unsigned)x0 < 64u)         mk |= 1;
        if ((unsigned)y0 < 64u && (unsigned)(x0+1) < 64u)     mk |= 2;
        if ((unsigned)(y0+1) < 64u && (unsigned)x0 < 64u)     mk |= 4;
        if ((unsigned)(y0+1) < 64u && (unsigned)(x0+1) < 64u) mk |= 8;
        int iy = y0 - ry0, ix = x0 - rx0;
        bool inreg = ((unsigned)iy <= (unsigned)(RROWS - 2)) &&
                     ((unsigned)ix <= (unsigned)(RCOLS - 2));
        int fl, zp;
        if (!mk)        { fl = 16; zp = 0; }
        else if (inreg) { fl = mk | 16; zp = iy * RCOLS + ix; }
        else            { fl = mk; zp = (y0 + 1) * 66 + (x0 + 1); }
        sGt[item] = (uint)f2h(ty) | ((uint)f2h(tx) << 16);
        sGz[item] = (zp << 5) | fl;
    }
    __syncthreads();

    // ---------------- P1: store S as fp16 (overwrites sOff) ----------------
#pragma unroll
    for (int nt = 0; nt < 5; ++nt) {
        int rp = nt * 16 + row;
        if (rp < RPX) {
#pragma unroll
            for (int r = 0; r < 4; ++r)
                sSW[wv_ * 16 + kb8 * 4 + r][rp] = f2h(sreg[nt][r]);
        }
    }
    __syncthreads();

    // ---------------- P2: attention logits ---------------------------------
    for (int item = tid; item < 576; item += 256) {
        int px = item / 9;
        uint gt = sGt[item];
        float ty = h2f((ushort)gt), tx = h2f((ushort)(gt >> 16));
        int z = sGz[item];
        int fl = z & 31;
        float a;
        if (fl & 16) {
            int zi = z >> 5;
            float w00 = (1.f - ty) * (1.f - tx), w01 = (1.f - ty) * tx;
            float w10 = ty * (1.f - tx), w11 = ty * tx;
            a  = (fl & 1) ? w00 * h2f(sSW[px][zi])             : 0.f;
            a += (fl & 2) ? w01 * h2f(sSW[px][zi + 1])         : 0.f;
            a += (fl & 4) ? w10 * h2f(sSW[px][zi + RCOLS])     : 0.f;
            a += (fl & 8) ? w11 * h2f(sSW[px][zi + RCOLS + 1]) : 0.f;
        } else {
            int t = z >> 5;
            int y0 = t / 66 - 1, x0 = t - (t / 66) * 66 - 1;
            a = 0.f;
#pragma unroll
            for (int c = 0; c < 4; ++c) if ((fl >> c) & 1) {
                int dy = c >> 1, dx = c & 1;
                float wgt = (dy ? ty : 1.f - ty) * (dx ? tx : 1.f - tx);
                const ushort* kr = &kbf[((size_t)b * 4096 + (y0 + dy) * 64 + x0 + dx) * 128 +
                                        g * EMB];
                float dot = 0.f;
                for (int e = 0; e < EMB; ++e) dot += bf2f(sQ[px][e]) * bf2f(kr[e]);
                a += wgt * dot;
            }
            int old = atomicAdd(&sFB[0], 1);
            if (old < 128) sFB[1 + old] = item;
        }
        sAttn[item] = a;
    }
    __syncthreads();

    // ---------------- P3: softmax (tid<64)  |  zero W (tid>=64) ------------
    if (tid < 64) {
        float aa[NPT];
        float mx = -1e30f;
#pragma unroll
        for (int p = 0; p < NPT; ++p) { aa[p] = sAttn[tid * 9 + p]; mx = fmaxf(mx, aa[p]); }
        float s = 0.f;
#pragma unroll
        for (int p = 0; p < NPT; ++p) { aa[p] = __expf(aa[p] - mx); s += aa[p]; }
        float inv = 1.f / s;
#pragma unroll
        for (int p = 0; p < NPT; ++p) sAttn[tid * 9 + p] = aa[p] * inv;
    } else {
        float4* p = (float4*)&sSW[0][0];
        float4 z4 = make_float4(0.f, 0.f, 0.f, 0.f);
        for (int i = tid - 64; i < 576; i += 192) p[i] = z4;
    }
    __syncthreads();

    // ---------------- P4: W-build (tid<64, serial fp16 RMW) ----------------
    if (tid < 64) {
        int px = tid;
#pragma unroll
        for (int pt = 0; pt < NPT; ++pt) {
            int item = px * 9 + pt;
            int z = sGz[item];
            int fl = z & 31;
            if (!(fl & 16)) continue;
            uint gt = sGt[item];
            float ty = h2f((ushort)gt), tx = h2f((ushort)(gt >> 16));
            float a = sAttn[item];
            int zi = z >> 5;
            ushort* c = &sSW[px][zi];
            if (fl & 1) c[0]         = f2h(h2f(c[0])         + (1.f-ty)*(1.f-tx)*a);
            if (fl & 2) c[1]         = f2h(h2f(c[1])         + (1.f-ty)*tx*a);
            if (fl & 4) c[RCOLS]     = f2h(h2f(c[RCOLS])     + ty*(1.f-tx)*a);
            if (fl & 8) c[RCOLS + 1] = f2h(h2f(c[RCOLS + 1]) + ty*tx*a);
        }
    }
    __syncthreads();

    // ---------------- P5: O-GEMM (f16 MFMA) + store -------------------------
    {
        half8v bfm[3][4];
#pragma unroll
        for (int kt = 0; kt < 3; ++kt)
#pragma unroll
            for (int nt = 0; nt < 4; ++nt)
                bfm[kt][nt] = *(const half8v*)&sXt[nt * 16 + row][kt * 32 + kb8 * 8];

        int px = wv_ * 16 + row;
        half8v af0 = *(const half8v*)&sSW[px][kb8 * 8];
        half8v af1 = *(const half8v*)&sSW[px][32 + kb8 * 8];
        half8v af2 = {0,0,0,0,0,0,0,0};
        if (kb8 == 0) af2 = *(const half8v*)&sSW[px][64];   // cols 66..71 zeroed

        f32x4 acc[4];
#pragma unroll
        for (int nt = 0; nt < 4; ++nt) { f32x4 z = {0.f,0.f,0.f,0.f}; acc[nt] = z; }
#pragma unroll
        for (int nt = 0; nt < 4; ++nt) {
            acc[nt] = __builtin_amdgcn_mfma_f32_16x16x32_f16(af0, bfm[0][nt], acc[nt], 0, 0, 0);
            acc[nt] = __builtin_amdgcn_mfma_f32_16x16x32_f16(af1, bfm[1][nt], acc[nt], 0, 0, 0);
            acc[nt] = __builtin_amdgcn_mfma_f32_16x16x32_f16(af2, bfm[2][nt], acc[nt], 0, 0, 0);
        }
        int hup = th * 4 + wv_;
#pragma unroll
        for (int nt = 0; nt < 4; ++nt) {
            int ch = nt * 16 + row;
            float* ob = out + ((size_t)b * 256 + g * CGRP + ch) * 16384 +
                        hup * 128 + tw * 16 + kb8 * 4;
#pragma unroll
            for (int r = 0; r < 4; ++r) ob[r] = acc[nt][r];
        }
    }
    __syncthreads();

    // ---------------- P6: rare out-of-region fallback -----------------------
    int nfb = min(sFB[0], 128);
    for (int i = 0; i < nfb; ++i) {
        if (tid < 64) {
            int item = sFB[1 + i];
            int px = item / 9;
            uint gt = sGt[item];
            float ty = h2f((ushort)gt), tx = h2f((ushort)(gt >> 16));
            int z = sGz[item];
            float a = sAttn[item];
            int fl = z & 15;
            int t = z >> 5;
            int y0 = t / 66 - 1, x0 = t - (t / 66) * 66 - 1;
            const float* xg = x + ((size_t)b * 256 + g * CGRP + tid) * 4096;
            float v = 0.f;
            if (fl & 1) v += (1.f-ty)*(1.f-tx)*a * xg[y0*64 + x0];
            if (fl & 2) v += (1.f-ty)*tx*a       * xg[y0*64 + x0 + 1];
            if (fl & 4) v += ty*(1.f-tx)*a       * xg[(y0+1)*64 + x0];
            if (fl & 8) v += ty*tx*a             * xg[(y0+1)*64 + x0 + 1];
            int hup = th * 4 + (px >> 4), wup = tw * 16 + (px & 15);
            float* op = out + ((size_t)b * 256 + g * CGRP + tid) * 16384 +
                        hup * 128 + wup;
            *op += v;
        }
    }
}

// ---------------------------------------------------------------------------
extern "C" void kernel_launch(void* const* d_in, const int* in_sizes, int n_in,
                              void* d_out, int out_size, void* d_ws, size_t ws_size,
                              hipStream_t stream)
{
    const float* y    = (const float*)d_in[0];
    const float* x    = (const float*)d_in[1];
    const float* Wq   = (const float*)d_in[2];
    const float* bq   = (const float*)d_in[3];
    const float* Wk   = (const float*)d_in[4];
    const float* bk   = (const float*)d_in[5];
    const float* Woff = (const float*)d_in[6];
    const float* boff = (const float*)d_in[7];
    float* out = (float*)d_out;

    // workspace layout (20.3 MB total)
    ushort* wqbf  = (ushort*)d_ws;                            // 128*256
    ushort* wkobf = wqbf + 128 * 256;                         // 512*256
    ushort* qbf   = wkobf + 512 * 256;                        // 2*16384*128
    ushort* kbf   = qbf + (size_t)B_N * 16384 * 128;          // 2*4096*128
    float*  offw  = (float*)(kbf + (size_t)B_N * 4096 * 128); // 2*4096*288

    // weights -> bf16 (zero-padded koff rows 416..511)
    convert_w_kernel<<<dim3(640), dim3(256), 0, stream>>>(Wq, Wk, Woff, wqbf, wkobf);

    // q = Wq @ y + bq  -> bf16 [B,16384,128]
    mfma_gemm<<<dim3(512), dim3(256), 0, stream>>>(
        y, wqbf, bq, nullptr, qbf, nullptr, 16384, 256, 1);

    // [k;off] = [Wk;Woff] @ x + [bk;boff] -> k bf16 [B,4096,128], off fp32 [B,4096,288]
    mfma_gemm<<<dim3(512), dim3(256), 0, stream>>>(
        x, wkobf, bk, boff, kbf, offw, 4096, 64, 4);

    // fused deformable attention
    deform_kernel<<<dim3(2048), dim3(256), 0, stream>>>(qbf, kbf, offw, x, out);
}

// Round 9
// 71.370 us; speedup vs baseline: 3.8883x; 1.1051x over previous
//
#include <hip/hip_runtime.h>

// Problem constants
#define B_N   2
#define H_LR  64
#define W_LR  64
#define HUP   128
#define WUP   128
#define GRP   4
#define NPT   9
#define EMB   32
#define CGRP  64
#define KIN   256
#define GE    128
#define NOFF  288

typedef __attribute__((ext_vector_type(8))) short short8v;
typedef _Float16 half8v __attribute__((ext_vector_type(8)));
typedef __attribute__((ext_vector_type(4))) float f32x4;

__device__ __forceinline__ ushort f2bf(float f) {
    unsigned u = __float_as_uint(f);
    u += 0x7FFFu + ((u >> 16) & 1u);
    return (ushort)(u >> 16);
}
__device__ __forceinline__ float bf2f(ushort h) {
    return __uint_as_float(((unsigned)h) << 16);
}
__device__ __forceinline__ ushort f2h(float f) {
    _Float16 h = (_Float16)f;
    return __builtin_bit_cast(ushort, h);
}
__device__ __forceinline__ float h2f(ushort u) {
    _Float16 h = __builtin_bit_cast(_Float16, u);
    return (float)h;
}

// ---------------------------------------------------------------------------
// Weight conversion: Wq -> wqbf [128][256]; [Wk;Woff;0] -> wkobf [512][256]
// ---------------------------------------------------------------------------
__global__ __launch_bounds__(256) void convert_w_kernel(
    const float* __restrict__ Wq, const float* __restrict__ Wk,
    const float* __restrict__ Woff, ushort* __restrict__ wqbf,
    ushort* __restrict__ wkobf)
{
    int r = blockIdx.x, k = threadIdx.x;
    if (r < 128) {
        wqbf[r * 256 + k] = f2bf(Wq[r * 256 + k]);
    } else {
        int r2 = r - 128;
        float v = 0.f;
        if (r2 < 128) v = Wk[r2 * 256 + k];
        else if (r2 < 416) v = Woff[(r2 - 128) * 256 + k];
        wkobf[r2 * 256 + k] = f2bf(v);
    }
}

// ---------------------------------------------------------------------------
// Merged bf16 MFMA GEMM for both 1x1 convs, register-prefetch pipelined.
// blocks [0,512):   q  = Wq@y+bq    M=16384, BM=64, BN=128 (1 ntile)
// blocks [512,1024): koff = [Wk;Woff]@x+b  M=4096, BM=64, 4 ntiles of 128
// 256 thr = 4 waves (2m x 2n); K-step 64; next tile loaded to regs during MFMA.
// ---------------------------------------------------------------------------
__global__ __launch_bounds__(256, 4) void mfma_gemm(
    const float* __restrict__ y, const float* __restrict__ x,
    const ushort* __restrict__ WQ, const ushort* __restrict__ WKO,
    const float* __restrict__ bq, const float* __restrict__ bk,
    const float* __restrict__ boff,
    ushort* __restrict__ qbf, ushort* __restrict__ kbf,
    float* __restrict__ offw)
{
    __shared__ __align__(16) ushort sY[64][68];
    __shared__ __align__(16) ushort sB[128][72];

    int bid = blockIdx.x;
    const float* SRC; const ushort* WBF; const float* ba; const float* bb;
    ushort* OBF; float* OFP;
    int M, m0, n0, b;
    if (bid < 512) {
        int mt = bid & 255; b = bid >> 8;
        SRC = y; WBF = WQ; ba = bq; bb = nullptr; OBF = qbf; OFP = nullptr;
        M = 16384; m0 = mt * 64; n0 = 0;
    } else {
        int r = bid - 512;
        int mt = r & 63, nt2 = (r >> 6) & 3; b = r >> 8;
        SRC = x; WBF = WKO; ba = bk; bb = boff; OBF = kbf; OFP = offw;
        M = 4096; m0 = mt * 64; n0 = nt2 * 128;
    }

    int tid = threadIdx.x;
    int lane = tid & 63;
    int wv = tid >> 6, wm = wv >> 1, wn = wv & 1;
    int il = lane & 15, g4 = lane >> 4;
    int st_m4 = tid & 15, st_c = tid >> 4;     // activation staging coords
    int st_c8 = tid & 7,  st_n = tid >> 3;     // weight staging coords

    f32x4 acc[2][4];
#pragma unroll
    for (int i = 0; i < 2; ++i)
#pragma unroll
        for (int j = 0; j < 4; ++j) { f32x4 z = {0.f,0.f,0.f,0.f}; acc[i][j] = z; }

    const float* src_b = SRC + (size_t)b * KIN * M;

    float4 ra[4]; short8v rb[4];
#pragma unroll
    for (int i = 0; i < 4; ++i)
        ra[i] = *(const float4*)&src_b[(size_t)(st_c + i * 16) * M + m0 + st_m4 * 4];
#pragma unroll
    for (int i = 0; i < 4; ++i)
        rb[i] = *(const short8v*)&WBF[(size_t)(n0 + st_n + i * 32) * KIN + st_c8 * 8];

    for (int ks = 0; ks < 4; ++ks) {
        // commit staged regs to LDS (convert activations to bf16)
#pragma unroll
        for (int i = 0; i < 4; ++i) {
            ushort4 h;
            h.x = f2bf(ra[i].x); h.y = f2bf(ra[i].y);
            h.z = f2bf(ra[i].z); h.w = f2bf(ra[i].w);
            *(ushort4*)&sY[st_c + i * 16][st_m4 * 4] = h;
            *(short8v*)&sB[st_n + i * 32][st_c8 * 8] = rb[i];
        }
        __syncthreads();
        if (ks < 3) {
            int k0 = (ks + 1) * 64;
#pragma unroll
            for (int i = 0; i < 4; ++i)
                ra[i] = *(const float4*)&src_b[(size_t)(k0 + st_c + i * 16) * M + m0 + st_m4 * 4];
#pragma unroll
            for (int i = 0; i < 4; ++i)
                rb[i] = *(const short8v*)&WBF[(size_t)(n0 + st_n + i * 32) * KIN + k0 + st_c8 * 8];
        }
#pragma unroll
        for (int kc = 0; kc < 2; ++kc) {
            int kb = kc * 32 + g4 * 8;
            short8v af[2], bfr[4];
#pragma unroll
            for (int mf = 0; mf < 2; ++mf) {
                int m = wm * 32 + mf * 16 + il;
                short8v t;
#pragma unroll
                for (int j = 0; j < 8; ++j) t[j] = (short)sY[kb + j][m];
                af[mf] = t;
            }
#pragma unroll
            for (int nf = 0; nf < 4; ++nf)
                bfr[nf] = *(const short8v*)&sB[wn * 64 + nf * 16 + il][kb];
#pragma unroll
            for (int mf = 0; mf < 2; ++mf)
#pragma unroll
                for (int nf = 0; nf < 4; ++nf)
                    acc[mf][nf] = __builtin_amdgcn_mfma_f32_16x16x32_bf16(
                        af[mf], bfr[nf], acc[mf][nf], 0, 0, 0);
        }
        __syncthreads();
    }

    // epilogue
#pragma unroll
    for (int mf = 0; mf < 2; ++mf) {
#pragma unroll
        for (int r = 0; r < 4; ++r) {
            int m = m0 + wm * 32 + mf * 16 + g4 * 4 + r;
            size_t row = (size_t)b * M + m;
#pragma unroll
            for (int nf = 0; nf < 4; ++nf) {
                int n = n0 + wn * 64 + nf * 16 + il;
                float v = acc[mf][nf][r];
                if (n < GE) {
                    OBF[row * 128 + n] = f2bf(v + ba[n]);
                } else {
                    int no = n - GE;
                    if (no < NOFF) OFP[row * 288 + no] = v + bb[no];
                }
            }
        }
    }
}

// ---------------------------------------------------------------------------
// Fused deformable attention via per-block dense MFMA GEMMs.
// Block = 256 thr = one (b,g) x 16x4 up-pixel tile; region = 6x11 LR pixels.
// Manual smem carve; sOT (fp32 out-transpose) aliases sXt+sK+sQ after P5.
// Coalesced x staging (quad-in-lane) and coalesced float4 output stores.
// ---------------------------------------------------------------------------
#define RROWS 6
#define RCOLS 11
#define RPX   66

__global__ __launch_bounds__(256, 4) void deform_kernel(
    const ushort* __restrict__ qbf,  // [B, 16384, 128] bf16 pixel-major
    const ushort* __restrict__ kbf,  // [B, 4096, 128] bf16 pixel-major
    const float* __restrict__ offw,  // [B, 4096, 288] fp32 pixel-major
    const float* __restrict__ x,     // [B, 256, 64, 64] channel-major (input)
    float* __restrict__ out)         // [B, 256, 128, 128]
{
    __shared__ __align__(16) char smem[36272];
    ushort (*sXt)[72] = (ushort(*)[72])(smem);            //  9216 B  x region fp16
    ushort (*sK)[40]  = (ushort(*)[40])(smem + 9216);     //  5280 B  k region bf16
    ushort (*sQ)[40]  = (ushort(*)[40])(smem + 14496);    //  5120 B  q bf16
    ushort (*sSW)[72] = (ushort(*)[72])(smem + 19616);    //  9216 B  off fp32 / S,W fp16
    uint*  sGt        = (uint*)(smem + 28832);            //  2304 B
    int*   sGz        = (int*)(smem + 31136);             //  2304 B
    float* sAttn      = (float*)(smem + 33440);           //  2304 B
    int*   sFB        = (int*)(smem + 35744);             //   516 B
    float (*sOT)[76]  = (float(*)[76])(smem);             // 19456 B alias (post-P5)
    float* sOff       = (float*)(smem + 19616);           // [16][72] fp32 alias

    int bx = blockIdx.x;
    int tw = bx & 7, th = (bx >> 3) & 31, g = (bx >> 8) & 3, b = bx >> 10;
    int tid = threadIdx.x;
    int wv_ = tid >> 6, lane = tid & 63;
    int row = lane & 15, kb8 = lane >> 4;

    const int ry0 = th * 2 - 2, rx0 = tw * 8 - 1;

    // ---------------- P0a: all staging (coalesced) -------------------------
    if (tid == 0) sFB[0] = 0;
    // zero sXt pad cols 66..71
    if (tid < 192) {
        int r = tid / 3, c2 = tid - (tid / 3) * 3;
        *(uint*)&sXt[r][66 + c2 * 2] = 0;
    }
    // x region -> fp16; item = (ch, gy, quad), quad in low lane bits -> 64B merge
    for (int it = tid; it < 1536; it += 256) {
        int quad = it & 3, rest = it >> 2;
        int ch = rest / 6, gy = rest - (rest / 6) * 6;
        int gyg = min(max(ry0 + gy, 0), 63);
        const float* xr = x + ((size_t)b * 256 + g * CGRP + ch) * 4096 + gyg * 64;
        if (tw >= 1 && tw <= 6) {
            float4 f = *(const float4*)&xr[rx0 - 3 + quad * 4];
            const float* fv = (const float*)&f;
#pragma unroll
            for (int j = 0; j < 4; ++j) {
                int col = quad * 4 + j - 3;
                if (col >= 0 && col < RCOLS) sXt[ch][gy * RCOLS + col] = f2h(fv[j]);
            }
        } else {
#pragma unroll
            for (int j = 0; j < 4; ++j) {
                int col = quad * 4 + j - 3;
                if (col >= 0 && col < RCOLS) {
                    int gxg = min(max(rx0 + col, 0), 63);
                    sXt[ch][gy * RCOLS + col] = f2h(xr[gxg]);
                }
            }
        }
    }
    // k region bf16 (4 consecutive lanes cover one 64B row chunk)
    for (int i = tid; i < 264; i += 256) {
        int rp = i >> 2, c4 = i & 3;
        int qy = rp / RCOLS, qx = rp - qy * RCOLS;
        int gy = min(max(ry0 + qy, 0), 63), gx = min(max(rx0 + qx, 0), 63);
        *(short8v*)&sK[rp][c4 * 8] =
            *(const short8v*)&kbf[((size_t)b * 4096 + gy * 64 + gx) * 128 +
                                  g * EMB + c4 * 8];
    }
    // q bf16
    {
        int px = tid >> 2, c4 = tid & 3;
        int hup = th * 4 + (px >> 4), wup = tw * 16 + (px & 15);
        *(short8v*)&sQ[px][c4 * 8] =
            *(const short8v*)&qbf[((size_t)b * 16384 + hup * 128 + wup) * 128 +
                                  g * EMB + c4 * 8];
    }
    // offsets (coalesced float4) -> sOff
    for (int i = tid; i < 288; i += 256) {
        int lr = i / 18, f4 = i - (i / 18) * 18;
        int yy = th * 2 + (lr >> 3), xx = tw * 8 + (lr & 7);
        *(float4*)&sOff[lr * 72 + f4 * 4] =
            *(const float4*)&offw[((size_t)b * 4096 + yy * 64 + xx) * 288 +
                                  g * 72 + f4 * 4];
    }
    __syncthreads();

    // ---------------- P0b: S-GEMM (to regs) + geometry ---------------------
    f32x4 sreg[5];
    {
        short8v a = *(const short8v*)&sQ[wv_ * 16 + row][kb8 * 8];
#pragma unroll
        for (int nt = 0; nt < 5; ++nt) {
            int rr = nt * 16 + row; if (rr > 65) rr = 65;   // tail clamp
            short8v bf = *(const short8v*)&sK[rr][kb8 * 8];
            f32x4 z = {0.f, 0.f, 0.f, 0.f};
            sreg[nt] = __builtin_amdgcn_mfma_f32_16x16x32_bf16(a, bf, z, 0, 0, 0);
        }
    }
    for (int item = tid; item < 576; item += 256) {
        int px = item / 9, pt = item - (item / 9) * 9;
        int lx = px & 15, ly = px >> 4;
        int hup = th * 4 + ly, wup = tw * 16 + lx;
        int lr = (ly >> 1) * 8 + (lx >> 1);
        int ij = ((hup & 1) << 1) | (wup & 1);
        float offy = sOff[lr * 72 + pt * 8 + ij];
        float offx = sOff[lr * 72 + pt * 8 + 4 + ij];
        float py  = offy + hup * 0.5f - 0.25f;
        float pxx = offx + wup * 0.5f - 0.25f;
        float y0f = floorf(py), x0f = floorf(pxx);
        float ty = py - y0f, tx = pxx - x0f;
        int y0 = (int)y0f, x0 = (int)x0f;
        int mk = 0;
        if ((unsigned)y0 < 64u && (unsigned)x0 < 64u)         mk |= 1;
        if ((unsigned)y0 < 64u && (unsigned)(x0+1) < 64u)     mk |= 2;
        if ((unsigned)(y0+1) < 64u && (unsigned)x0 < 64u)     mk |= 4;
        if ((unsigned)(y0+1) < 64u && (unsigned)(x0+1) < 64u) mk |= 8;
        int iy = y0 - ry0, ix = x0 - rx0;
        bool inreg = ((unsigned)iy <= (unsigned)(RROWS - 2)) &&
                     ((unsigned)ix <= (unsigned)(RCOLS - 2));
        int fl, zp;
        if (!mk)        { fl = 16; zp = 0; }
        else if (inreg) { fl = mk | 16; zp = iy * RCOLS + ix; }
        else            { fl = mk; zp = (y0 + 1) * 66 + (x0 + 1); }
        sGt[item] = (uint)f2h(ty) | ((uint)f2h(tx) << 16);
        sGz[item] = (zp << 5) | fl;
    }
    __syncthreads();

    // ---------------- P1: store S as fp16 (overwrites sOff) ----------------
#pragma unroll
    for (int nt = 0; nt < 5; ++nt) {
        int rp = nt * 16 + row;
        if (rp < RPX) {
#pragma unroll
            for (int r = 0; r < 4; ++r)
                sSW[wv_ * 16 + kb8 * 4 + r][rp] = f2h(sreg[nt][r]);
        }
    }
    __syncthreads();

    // ---------------- P2: attention logits ---------------------------------
    for (int item = tid; item < 576; item += 256) {
        int px = item / 9;
        uint gt = sGt[item];
        float ty = h2f((ushort)gt), tx = h2f((ushort)(gt >> 16));
        int z = sGz[item];
        int fl = z & 31;
        float a;
        if (fl & 16) {
            int zi = z >> 5;
            float w00 = (1.f - ty) * (1.f - tx), w01 = (1.f - ty) * tx;
            float w10 = ty * (1.f - tx), w11 = ty * tx;
            a  = (fl & 1) ? w00 * h2f(sSW[px][zi])             : 0.f;
            a += (fl & 2) ? w01 * h2f(sSW[px][zi + 1])         : 0.f;
            a += (fl & 4) ? w10 * h2f(sSW[px][zi + RCOLS])     : 0.f;
            a += (fl & 8) ? w11 * h2f(sSW[px][zi + RCOLS + 1]) : 0.f;
        } else {
            int t = z >> 5;
            int y0 = t / 66 - 1, x0 = t - (t / 66) * 66 - 1;
            a = 0.f;
#pragma unroll
            for (int c = 0; c < 4; ++c) if ((fl >> c) & 1) {
                int dy = c >> 1, dx = c & 1;
                float wgt = (dy ? ty : 1.f - ty) * (dx ? tx : 1.f - tx);
                const ushort* kr = &kbf[((size_t)b * 4096 + (y0 + dy) * 64 + x0 + dx) * 128 +
                                        g * EMB];
                float dot = 0.f;
                for (int e = 0; e < EMB; ++e) dot += bf2f(sQ[px][e]) * bf2f(kr[e]);
                a += wgt * dot;
            }
            int old = atomicAdd(&sFB[0], 1);
            if (old < 128) sFB[1 + old] = item;
        }
        sAttn[item] = a;
    }
    __syncthreads();

    // ---------------- P3: softmax (tid<64)  |  zero W (tid>=64) ------------
    if (tid < 64) {
        float aa[NPT];
        float mx = -1e30f;
#pragma unroll
        for (int p = 0; p < NPT; ++p) { aa[p] = sAttn[tid * 9 + p]; mx = fmaxf(mx, aa[p]); }
        float s = 0.f;
#pragma unroll
        for (int p = 0; p < NPT; ++p) { aa[p] = __expf(aa[p] - mx); s += aa[p]; }
        float inv = 1.f / s;
#pragma unroll
        for (int p = 0; p < NPT; ++p) sAttn[tid * 9 + p] = aa[p] * inv;
    } else {
        float4* p = (float4*)&sSW[0][0];
        float4 z4 = make_float4(0.f, 0.f, 0.f, 0.f);
        for (int i = tid - 64; i < 576; i += 192) p[i] = z4;
    }
    __syncthreads();

    // ---------------- P4: W-build (tid<64, serial fp16 RMW) ----------------
    if (tid < 64) {
        int px = tid;
#pragma unroll
        for (int pt = 0; pt < NPT; ++pt) {
            int item = px * 9 + pt;
            int z = sGz[item];
            int fl = z & 31;
            if (!(fl & 16)) continue;
            uint gt = sGt[item];
            float ty = h2f((ushort)gt), tx = h2f((ushort)(gt >> 16));
            float a = sAttn[item];
            int zi = z >> 5;
            ushort* c = &sSW[px][zi];
            if (fl & 1) c[0]         = f2h(h2f(c[0])         + (1.f-ty)*(1.f-tx)*a);
            if (fl & 2) c[1]         = f2h(h2f(c[1])         + (1.f-ty)*tx*a);
            if (fl & 4) c[RCOLS]     = f2h(h2f(c[RCOLS])     + ty*(1.f-tx)*a);
            if (fl & 8) c[RCOLS + 1] = f2h(h2f(c[RCOLS + 1]) + ty*tx*a);
        }
    }
    __syncthreads();

    // ---------------- P5: O-GEMM (f16 MFMA) --------------------------------
    f32x4 oacc[4];
    {
        half8v bfm0[4], bfm1[4], bfm2[4];
#pragma unroll
        for (int nt = 0; nt < 4; ++nt) {
            bfm0[nt] = *(const half8v*)&sXt[nt * 16 + row][kb8 * 8];
            bfm1[nt] = *(const half8v*)&sXt[nt * 16 + row][32 + kb8 * 8];
            bfm2[nt] = *(const half8v*)&sXt[nt * 16 + row][64];  // finite; x af2=0 for kb8>0
        }
        int px = wv_ * 16 + row;
        half8v af0 = *(const half8v*)&sSW[px][kb8 * 8];
        half8v af1 = *(const half8v*)&sSW[px][32 + kb8 * 8];
        half8v af2 = {0,0,0,0,0,0,0,0};
        if (kb8 == 0) af2 = *(const half8v*)&sSW[px][64];   // cols 66..71 zeroed

#pragma unroll
        for (int nt = 0; nt < 4; ++nt) { f32x4 z = {0.f,0.f,0.f,0.f}; oacc[nt] = z; }
#pragma unroll
        for (int nt = 0; nt < 4; ++nt) {
            oacc[nt] = __builtin_amdgcn_mfma_f32_16x16x32_f16(af0, bfm0[nt], oacc[nt], 0, 0, 0);
            oacc[nt] = __builtin_amdgcn_mfma_f32_16x16x32_f16(af1, bfm1[nt], oacc[nt], 0, 0, 0);
            oacc[nt] = __builtin_amdgcn_mfma_f32_16x16x32_f16(af2, bfm2[nt], oacc[nt], 0, 0, 0);
        }
    }
    __syncthreads();           // all sXt/sSW/sK/sQ reads done; safe to alias sOT

    // transpose to sOT[ch][hupl*16 + wupl]
#pragma unroll
    for (int nt = 0; nt < 4; ++nt)
        *(f32x4*)&sOT[nt * 16 + row][wv_ * 16 + kb8 * 4] = oacc[nt];
    __syncthreads();

    // coalesced stores: 4 lanes complete one 64B line per instruction
    {
#pragma unroll
        for (int i = 0; i < 4; ++i) {
            int pr = i * 64 + (tid >> 2);
            int ch = pr >> 2, hupl = pr & 3, q = tid & 3;
            float4 v = *(float4*)&sOT[ch][hupl * 16 + q * 4];
            *(float4*)(out + ((size_t)b * 256 + g * CGRP + ch) * 16384 +
                       (size_t)(th * 4 + hupl) * 128 + tw * 16 + q * 4) = v;
        }
    }
    __syncthreads();

    // ---------------- P6: rare out-of-region fallback -----------------------
    int nfb = min(sFB[0], 128);
    for (int i = 0; i < nfb; ++i) {
        if (tid < 64) {
            int item = sFB[1 + i];
            int px = item / 9;
            uint gt = sGt[item];
            float ty = h2f((ushort)gt), tx = h2f((ushort)(gt >> 16));
            int z = sGz[item];
            float a = sAttn[item];
            int fl = z & 15;
            int t = z >> 5;
            int y0 = t / 66 - 1, x0 = t - (t / 66) * 66 - 1;
            const float* xg = x + ((size_t)b * 256 + g * CGRP + tid) * 4096;
            float v = 0.f;
            if (fl & 1) v += (1.f-ty)*(1.f-tx)*a * xg[y0*64 + x0];
            if (fl & 2) v += (1.f-ty)*tx*a       * xg[y0*64 + x0 + 1];
            if (fl & 4) v += ty*(1.f-tx)*a       * xg[(y0+1)*64 + x0];
            if (fl & 8) v += ty*tx*a             * xg[(y0+1)*64 + x0 + 1];
            int hup = th * 4 + (px >> 4), wup = tw * 16 + (px & 15);
            float* op = out + ((size_t)b * 256 + g * CGRP + tid) * 16384 +
                        hup * 128 + wup;
            *op += v;
        }
    }
}

// ---------------------------------------------------------------------------
extern "C" void kernel_launch(void* const* d_in, const int* in_sizes, int n_in,
                              void* d_out, int out_size, void* d_ws, size_t ws_size,
                              hipStream_t stream)
{
    const float* y    = (const float*)d_in[0];
    const float* x    = (const float*)d_in[1];
    const float* Wq   = (const float*)d_in[2];
    const float* bq   = (const float*)d_in[3];
    const float* Wk   = (const float*)d_in[4];
    const float* bk   = (const float*)d_in[5];
    const float* Woff = (const float*)d_in[6];
    const float* boff = (const float*)d_in[7];
    float* out = (float*)d_out;

    // workspace layout (20.3 MB total)
    ushort* wqbf  = (ushort*)d_ws;                            // 128*256
    ushort* wkobf = wqbf + 128 * 256;                         // 512*256
    ushort* qbf   = wkobf + 512 * 256;                        // 2*16384*128
    ushort* kbf   = qbf + (size_t)B_N * 16384 * 128;          // 2*4096*128
    float*  offw  = (float*)(kbf + (size_t)B_N * 4096 * 128); // 2*4096*288

    // weights -> bf16 (zero-padded koff rows 416..511)
    convert_w_kernel<<<dim3(640), dim3(256), 0, stream>>>(Wq, Wk, Woff, wqbf, wkobf);

    // both convs in one pipelined launch
    mfma_gemm<<<dim3(1024), dim3(256), 0, stream>>>(
        y, x, wqbf, wkobf, bq, bk, boff, qbf, kbf, offw);

    // fused deformable attention
    deform_kernel<<<dim3(2048), dim3(256), 0, stream>>>(qbf, kbf, offw, x, out);
}